// Round 1
// baseline (106304.163 us; speedup 1.0000x reference)
//
#include <hip/hip_runtime.h>
#include <math.h>

#define N_IMG 64
#define S_LEN 257
#define D_MODEL 768
#define H_HEADS 12
#define DHEAD 64
#define L_LAYERS 12
#define F_HID 3072
#define F_CHUNK 1536
#define OUT_DIM 10
#define R_ROWS (N_IMG * S_LEN)  // 16448

// ---------------- positional embedding (double precision, matches numpy f64) ----------------
__global__ __launch_bounds__(256) void pos_kernel(float* __restrict__ pos) {
    int i = blockIdx.x;          // 0..256
    int t = threadIdx.x;
    for (int u = 0; u < 3; ++u) {
        int j = t + 256 * u;
        double e = (double)(j & ~1) / 768.0;                 // (j - j%2)/d
        double angle = (double)i * exp(-e * 9.210340371976184);  // i / 10000^e
        double v = (j & 1) ? cos(angle) : sin(angle);
        pos[i * 768 + j] = (float)v;
    }
}

// ---------------- patch embed + cls + pos ----------------
__global__ __launch_bounds__(256) void embed_kernel(const float* __restrict__ images,
                                                    const float* __restrict__ Wemb,
                                                    const float* __restrict__ bemb,
                                                    const float* __restrict__ cls,
                                                    const float* __restrict__ pos,
                                                    float* __restrict__ tok) {
    int b = blockIdx.x;                 // n*257 + s
    int n = b / S_LEN, s = b % S_LEN;
    int t = threadIdx.x;
    __shared__ float p[16];
    if (s > 0 && t < 16) p[t] = images[n * 4096 + (s - 1) * 16 + t];
    __syncthreads();
    for (int u = 0; u < 3; ++u) {
        int d = t + 256 * u;
        float acc;
        if (s == 0) {
            acc = cls[d];
        } else {
            acc = bemb[d];
            const float4* w = (const float4*)(Wemb + d * 16);
            float4 w0 = w[0], w1 = w[1], w2 = w[2], w3 = w[3];
            acc += p[0] * w0.x + p[1] * w0.y + p[2] * w0.z + p[3] * w0.w;
            acc += p[4] * w1.x + p[5] * w1.y + p[6] * w1.z + p[7] * w1.w;
            acc += p[8] * w2.x + p[9] * w2.y + p[10] * w2.z + p[11] * w2.w;
            acc += p[12] * w3.x + p[13] * w3.y + p[14] * w3.z + p[15] * w3.w;
        }
        tok[(size_t)b * 768 + d] = acc + pos[s * 768 + d];
    }
}

// ---------------- layernorm (one row / block) ----------------
__global__ __launch_bounds__(256) void ln_kernel(const float* __restrict__ x,
                                                 const float* __restrict__ g,
                                                 const float* __restrict__ b,
                                                 float* __restrict__ y) {
    int row = blockIdx.x;
    int t = threadIdx.x;
    const float* xr = x + (size_t)row * 768;
    float v0 = xr[t], v1 = xr[t + 256], v2 = xr[t + 512];
    float s = v0 + v1 + v2;
    float sq = v0 * v0 + v1 * v1 + v2 * v2;
    for (int o = 32; o; o >>= 1) {
        s += __shfl_xor(s, o);
        sq += __shfl_xor(sq, o);
    }
    __shared__ float red[8];
    if ((t & 63) == 0) { red[(t >> 6) * 2] = s; red[(t >> 6) * 2 + 1] = sq; }
    __syncthreads();
    float ts = red[0] + red[2] + red[4] + red[6];
    float tq = red[1] + red[3] + red[5] + red[7];
    float mu = ts * (1.0f / 768.0f);
    float var = tq * (1.0f / 768.0f) - mu * mu;
    float rs = rsqrtf(var + 1e-5f);
    float* yr = y + (size_t)row * 768;
    yr[t]       = (v0 - mu) * rs * g[t]       + b[t];
    yr[t + 256] = (v1 - mu) * rs * g[t + 256] + b[t + 256];
    yr[t + 512] = (v2 - mu) * rs * g[t + 512] + b[t + 512];
}

// ---------------- fused QKV: one block per (n, h) ----------------
__global__ __launch_bounds__(256) void qkv_kernel(const float* __restrict__ xln,
                                                  const float* __restrict__ Wq, const float* __restrict__ bq,
                                                  const float* __restrict__ Wk, const float* __restrict__ bk,
                                                  const float* __restrict__ Wv, const float* __restrict__ bv,
                                                  float* __restrict__ q, float* __restrict__ k,
                                                  float* __restrict__ v) {
    int nh = blockIdx.x;
    int h = nh % H_HEADS, n = nh / H_HEADS;
    int t = threadIdx.x;
    int tj = t & 63, tg = t >> 6;
    __shared__ float Wqs[64][65], Wks[64][65], Wvs[64][65];
    __shared__ float As[4][64];
    for (int u = 0; u < 16; ++u) {
        int idx = t + 256 * u;
        int o = idx >> 6, d = idx & 63;
        Wqs[d][o] = Wq[(h * 64 + o) * 64 + d];
        Wks[d][o] = Wk[(h * 64 + o) * 64 + d];
        Wvs[d][o] = Wv[(h * 64 + o) * 64 + d];
    }
    float bqv = bq[h * 64 + tj], bkv = bk[h * 64 + tj], bvv = bv[h * 64 + tj];
    __syncthreads();
    for (int it = 0; it < 65; ++it) {
        int s = it * 4 + tg;
        bool valid = s < S_LEN;
        int sv = valid ? s : S_LEN - 1;
        As[tg][tj] = xln[((size_t)n * S_LEN + sv) * 768 + h * 64 + tj];
        __syncthreads();
        float aq = 0, ak = 0, av = 0;
#pragma unroll
        for (int d = 0; d < 64; ++d) {
            float a = As[tg][d];
            aq += a * Wqs[d][tj];
            ak += a * Wks[d][tj];
            av += a * Wvs[d][tj];
        }
        if (valid) {
            size_t base = (((size_t)n * S_LEN + s) * H_HEADS + h) * 64 + tj;
            q[base] = (aq + bqv) * 0.125f;   // pre-apply 1/sqrt(64)
            k[base] = ak + bkv;
            v[base] = av + bvv;
        }
        __syncthreads();
    }
}

// ---------------- fused attention: one wave per q-row ----------------
__global__ __launch_bounds__(256) void attn_kernel(const float* __restrict__ q,
                                                   const float* __restrict__ k,
                                                   const float* __restrict__ v,
                                                   float* __restrict__ tok) {
    int b = blockIdx.x;
    int tile = b % 65;
    int nh = b / 65;
    int h = nh % H_HEADS, n = nh / H_HEADS;
    int t = threadIdx.x, w = t >> 6, lane = t & 63;
    int s = tile * 4 + w;
    bool active = s < S_LEN;
    int sv = active ? s : S_LEN - 1;
    __shared__ float qs[4][64];
    __shared__ float sc[4][257];
    const float* qrow = q + (((size_t)n * S_LEN + sv) * H_HEADS + h) * 64;
    qs[w][lane] = qrow[lane];
    __syncthreads();
    float scores[5];
    float lmax = -INFINITY;
    const float* kbase = k + ((size_t)n * S_LEN * H_HEADS + h) * 64;
#pragma unroll
    for (int m = 0; m < 5; ++m) {
        int kk = m * 64 + lane;
        float sco = -INFINITY;
        if (kk < S_LEN) {
            const float* krow = kbase + (size_t)kk * 768;
            float acc = 0.f;
#pragma unroll
            for (int d4 = 0; d4 < 16; ++d4) {
                float4 kv4 = *(const float4*)(krow + d4 * 4);
                acc += qs[w][d4 * 4 + 0] * kv4.x + qs[w][d4 * 4 + 1] * kv4.y +
                       qs[w][d4 * 4 + 2] * kv4.z + qs[w][d4 * 4 + 3] * kv4.w;
            }
            sco = acc;
        }
        scores[m] = sco;
        lmax = fmaxf(lmax, sco);
    }
    for (int o = 32; o; o >>= 1) lmax = fmaxf(lmax, __shfl_xor(lmax, o));
    float lsum = 0.f;
#pragma unroll
    for (int m = 0; m < 5; ++m) {
        int kk = m * 64 + lane;
        if (kk < S_LEN) {
            float e = expf(scores[m] - lmax);
            sc[w][kk] = e;
            lsum += e;
        }
    }
    for (int o = 32; o; o >>= 1) lsum += __shfl_xor(lsum, o);
    float inv = 1.0f / lsum;
    __syncthreads();
    const float* vbase = v + ((size_t)n * S_LEN * H_HEADS + h) * 64;
    float acc = 0.f;
    for (int kk = 0; kk < S_LEN; ++kk) {
        acc += sc[w][kk] * vbase[(size_t)kk * 768 + lane];
    }
    if (active) tok[((size_t)n * S_LEN + s) * 768 + h * 64 + lane] += acc * inv;
}

// ---------------- tiled fp32 GEMM: C(MxN) = [gelu](A @ B^T + bias) [+= C] ----------------
__device__ __forceinline__ float gelu_exact(float x) {
    return 0.5f * x * (1.0f + erff(x * 0.70710678118654752f));
}

template <bool GELU, bool ACCUM>
__global__ __launch_bounds__(256) void gemm_kernel(const float* __restrict__ A,
                                                   const float* __restrict__ B,
                                                   const float* __restrict__ bias,
                                                   float* __restrict__ C,
                                                   int K, int lda, int ldb, int ldc) {
    __shared__ float As[16][68];
    __shared__ float Bs[16][68];
    int t = threadIdx.x;
    int bx = blockIdx.x, by = blockIdx.y;
    int lrow = t >> 2, lk4 = (t & 3) * 4;
    const float* Ap = A + ((size_t)by * 64 + lrow) * lda + lk4;
    const float* Bp = B + ((size_t)bx * 64 + lrow) * ldb + lk4;
    int tc = t & 15, tr = t >> 4;
    float acc[4][4] = {};
    for (int kt = 0; kt < K; kt += 16) {
        float4 a4 = *(const float4*)(Ap + kt);
        float4 b4 = *(const float4*)(Bp + kt);
        __syncthreads();
        As[lk4 + 0][lrow] = a4.x; As[lk4 + 1][lrow] = a4.y;
        As[lk4 + 2][lrow] = a4.z; As[lk4 + 3][lrow] = a4.w;
        Bs[lk4 + 0][lrow] = b4.x; Bs[lk4 + 1][lrow] = b4.y;
        Bs[lk4 + 2][lrow] = b4.z; Bs[lk4 + 3][lrow] = b4.w;
        __syncthreads();
#pragma unroll
        for (int kk = 0; kk < 16; ++kk) {
            const float4 av = *(const float4*)(&As[kk][tr * 4]);
            const float4 bv = *(const float4*)(&Bs[kk][tc * 4]);
            acc[0][0] += av.x * bv.x; acc[0][1] += av.x * bv.y; acc[0][2] += av.x * bv.z; acc[0][3] += av.x * bv.w;
            acc[1][0] += av.y * bv.x; acc[1][1] += av.y * bv.y; acc[1][2] += av.y * bv.z; acc[1][3] += av.y * bv.w;
            acc[2][0] += av.z * bv.x; acc[2][1] += av.z * bv.y; acc[2][2] += av.z * bv.z; acc[2][3] += av.z * bv.w;
            acc[3][0] += av.w * bv.x; acc[3][1] += av.w * bv.y; acc[3][2] += av.w * bv.z; acc[3][3] += av.w * bv.w;
        }
    }
    int c0 = bx * 64 + tc * 4;
    float bsv[4] = {0.f, 0.f, 0.f, 0.f};
    if (bias) {
#pragma unroll
        for (int j = 0; j < 4; ++j) bsv[j] = bias[c0 + j];
    }
#pragma unroll
    for (int i = 0; i < 4; ++i) {
        int row = by * 64 + tr * 4 + i;
        float4 outv;
        outv.x = acc[i][0] + bsv[0];
        outv.y = acc[i][1] + bsv[1];
        outv.z = acc[i][2] + bsv[2];
        outv.w = acc[i][3] + bsv[3];
        if (GELU) {
            outv.x = gelu_exact(outv.x); outv.y = gelu_exact(outv.y);
            outv.z = gelu_exact(outv.z); outv.w = gelu_exact(outv.w);
        }
        float* Cp = C + (size_t)row * ldc + c0;
        if (ACCUM) {
            float4 old = *(const float4*)Cp;
            outv.x += old.x; outv.y += old.y; outv.z += old.z; outv.w += old.w;
        }
        *(float4*)Cp = outv;
    }
}

// ---------------- classifier head + softmax ----------------
__global__ __launch_bounds__(64) void head_kernel(const float* __restrict__ tok,
                                                  const float* __restrict__ Whead,
                                                  const float* __restrict__ bhead,
                                                  float* __restrict__ out) {
    int n = blockIdx.x;
    int t = threadIdx.x;
    __shared__ float logits[OUT_DIM];
    if (t < OUT_DIM) {
        float acc = bhead[t];
        const float* xr = tok + (size_t)n * S_LEN * 768;
        const float* w = Whead + t * 768;
        for (int d = 0; d < 768; ++d) acc += xr[d] * w[d];
        logits[t] = acc;
    }
    __syncthreads();
    if (t == 0) {
        float m = -INFINITY;
        for (int o = 0; o < OUT_DIM; ++o) m = fmaxf(m, logits[o]);
        float ssum = 0.f;
        float e[OUT_DIM];
        for (int o = 0; o < OUT_DIM; ++o) { e[o] = expf(logits[o] - m); ssum += e[o]; }
        float inv = 1.0f / ssum;
        for (int o = 0; o < OUT_DIM; ++o) out[n * OUT_DIM + o] = e[o] * inv;
    }
}

extern "C" void kernel_launch(void* const* d_in, const int* in_sizes, int n_in,
                              void* d_out, int out_size, void* d_ws, size_t ws_size,
                              hipStream_t stream) {
    const float* images = (const float*)d_in[0];
    const float* Wemb   = (const float*)d_in[1];
    const float* bemb   = (const float*)d_in[2];
    const float* cls    = (const float*)d_in[3];
    const float* Wq     = (const float*)d_in[4];
    const float* bq     = (const float*)d_in[5];
    const float* Wk     = (const float*)d_in[6];
    const float* bk     = (const float*)d_in[7];
    const float* Wv     = (const float*)d_in[8];
    const float* bv     = (const float*)d_in[9];
    const float* ln1_g  = (const float*)d_in[10];
    const float* ln1_b  = (const float*)d_in[11];
    const float* ln2_g  = (const float*)d_in[12];
    const float* ln2_b  = (const float*)d_in[13];
    const float* W1     = (const float*)d_in[14];
    const float* b1     = (const float*)d_in[15];
    const float* W2     = (const float*)d_in[16];
    const float* b2     = (const float*)d_in[17];
    const float* Whead  = (const float*)d_in[18];
    const float* bhead  = (const float*)d_in[19];
    float* out = (float*)d_out;

    const size_t TOKSZ = (size_t)R_ROWS * D_MODEL;  // 12,632,064
    float* ws  = (float*)d_ws;
    float* pos = ws;
    float* tok = pos + 257 * 768;
    float* xln = tok + TOKSZ;
    float* qb  = xln + TOKSZ;
    float* kb  = qb + TOKSZ;
    float* vb  = kb + TOKSZ;
    float* hid = qb;  // reuse q/k/v region for MLP hidden chunk (25.3M <= 37.9M floats)

    pos_kernel<<<S_LEN, 256, 0, stream>>>(pos);
    embed_kernel<<<R_ROWS, 256, 0, stream>>>(images, Wemb, bemb, cls, pos, tok);

    for (int l = 0; l < L_LAYERS; ++l) {
        const size_t wqkv_off = (size_t)l * H_HEADS * 64 * 64;
        const size_t bqkv_off = (size_t)l * H_HEADS * 64;
        ln_kernel<<<R_ROWS, 256, 0, stream>>>(tok, ln1_g + l * 768, ln1_b + l * 768, xln);
        qkv_kernel<<<N_IMG * H_HEADS, 256, 0, stream>>>(
            xln, Wq + wqkv_off, bq + bqkv_off, Wk + wqkv_off, bk + bqkv_off,
            Wv + wqkv_off, bv + bqkv_off, qb, kb, vb);
        attn_kernel<<<N_IMG * H_HEADS * 65, 256, 0, stream>>>(qb, kb, vb, tok);
        ln_kernel<<<R_ROWS, 256, 0, stream>>>(tok, ln2_g + l * 768, ln2_b + l * 768, xln);
        for (int c = 0; c < 2; ++c) {
            int c0 = c * F_CHUNK;
            gemm_kernel<true, false><<<dim3(F_CHUNK / 64, R_ROWS / 64), 256, 0, stream>>>(
                xln, W1 + (size_t)l * F_HID * D_MODEL + (size_t)c0 * D_MODEL,
                b1 + (size_t)l * F_HID + c0, hid, D_MODEL, D_MODEL, D_MODEL, F_CHUNK);
            gemm_kernel<false, true><<<dim3(D_MODEL / 64, R_ROWS / 64), 256, 0, stream>>>(
                hid, W2 + (size_t)l * D_MODEL * F_HID + c0,
                (c == 0) ? (b2 + (size_t)l * D_MODEL) : (const float*)nullptr,
                tok, F_CHUNK, F_CHUNK, F_HID, D_MODEL);
        }
    }
    head_kernel<<<N_IMG, 64, 0, stream>>>(tok, Whead, bhead, out);
}

// Round 2
// 35756.940 us; speedup vs baseline: 2.9730x; 2.9730x over previous
//
#include <hip/hip_runtime.h>
#include <math.h>

#define N_IMG 64
#define S_LEN 257
#define D_MODEL 768
#define H_HEADS 12
#define L_LAYERS 12
#define F_HID 3072
#define F_CHUNK 1536
#define OUT_DIM 10
#define R_ROWS (N_IMG * S_LEN)   // 16448
#define R_PAD 16512              // 129 * 128

typedef unsigned short ushort_t;
typedef __attribute__((ext_vector_type(4))) float f32x4;
typedef __attribute__((ext_vector_type(8))) short short8;

__device__ __forceinline__ ushort_t f2bf(float x) {
    unsigned u = __float_as_uint(x);
    u += 0x7fffu + ((u >> 16) & 1u);
    return (ushort_t)(u >> 16);
}

// ---------------- positional embedding (double precision, matches numpy f64) ----------------
__global__ __launch_bounds__(256) void pos_kernel(float* __restrict__ pos) {
    int i = blockIdx.x;
    int t = threadIdx.x;
    for (int u = 0; u < 3; ++u) {
        int j = t + 256 * u;
        double e = (double)(j & ~1) / 768.0;
        double angle = (double)i * exp(-e * 9.210340371976184);
        double v = (j & 1) ? cos(angle) : sin(angle);
        pos[i * 768 + j] = (float)v;
    }
}

// ---------------- patch embed + cls + pos ----------------
__global__ __launch_bounds__(256) void embed_kernel(const float* __restrict__ images,
                                                    const float* __restrict__ Wemb,
                                                    const float* __restrict__ bemb,
                                                    const float* __restrict__ cls,
                                                    const float* __restrict__ pos,
                                                    float* __restrict__ tok) {
    int b = blockIdx.x;
    int n = b / S_LEN, s = b % S_LEN;
    int t = threadIdx.x;
    __shared__ float p[16];
    if (s > 0 && t < 16) p[t] = images[n * 4096 + (s - 1) * 16 + t];
    __syncthreads();
    for (int u = 0; u < 3; ++u) {
        int d = t + 256 * u;
        float acc;
        if (s == 0) {
            acc = cls[d];
        } else {
            acc = bemb[d];
            const float4* w = (const float4*)(Wemb + d * 16);
            float4 w0 = w[0], w1 = w[1], w2 = w[2], w3 = w[3];
            acc += p[0] * w0.x + p[1] * w0.y + p[2] * w0.z + p[3] * w0.w;
            acc += p[4] * w1.x + p[5] * w1.y + p[6] * w1.z + p[7] * w1.w;
            acc += p[8] * w2.x + p[9] * w2.y + p[10] * w2.z + p[11] * w2.w;
            acc += p[12] * w3.x + p[13] * w3.y + p[14] * w3.z + p[15] * w3.w;
        }
        tok[(size_t)b * 768 + d] = acc + pos[s * 768 + d];
    }
}

// ---------------- layernorm: fp32 or bf16 output ----------------
template <bool BF>
__global__ __launch_bounds__(256) void ln_kernel(const float* __restrict__ x,
                                                 const float* __restrict__ g,
                                                 const float* __restrict__ b,
                                                 void* __restrict__ y) {
    int row = blockIdx.x;
    int t = threadIdx.x;
    const float* xr = x + (size_t)row * 768;
    float v0 = xr[t], v1 = xr[t + 256], v2 = xr[t + 512];
    float s = v0 + v1 + v2;
    float sq = v0 * v0 + v1 * v1 + v2 * v2;
    for (int o = 32; o; o >>= 1) {
        s += __shfl_xor(s, o);
        sq += __shfl_xor(sq, o);
    }
    __shared__ float red[8];
    if ((t & 63) == 0) { red[(t >> 6) * 2] = s; red[(t >> 6) * 2 + 1] = sq; }
    __syncthreads();
    float ts = red[0] + red[2] + red[4] + red[6];
    float tq = red[1] + red[3] + red[5] + red[7];
    float mu = ts * (1.0f / 768.0f);
    float var = tq * (1.0f / 768.0f) - mu * mu;
    float rs = rsqrtf(var + 1e-5f);
    float o0 = (v0 - mu) * rs * g[t] + b[t];
    float o1 = (v1 - mu) * rs * g[t + 256] + b[t + 256];
    float o2 = (v2 - mu) * rs * g[t + 512] + b[t + 512];
    if (BF) {
        ushort_t* yr = (ushort_t*)y + (size_t)row * 768;
        yr[t] = f2bf(o0); yr[t + 256] = f2bf(o1); yr[t + 512] = f2bf(o2);
    } else {
        float* yr = (float*)y + (size_t)row * 768;
        yr[t] = o0; yr[t + 256] = o1; yr[t + 512] = o2;
    }
}

// ---------------- fused QKV: one block per (n, h) ----------------
__global__ __launch_bounds__(256) void qkv_kernel(const float* __restrict__ xln,
                                                  const float* __restrict__ Wq, const float* __restrict__ bq,
                                                  const float* __restrict__ Wk, const float* __restrict__ bk,
                                                  const float* __restrict__ Wv, const float* __restrict__ bv,
                                                  float* __restrict__ q, float* __restrict__ k,
                                                  float* __restrict__ v) {
    int nh = blockIdx.x;
    int h = nh % H_HEADS, n = nh / H_HEADS;
    int t = threadIdx.x;
    int tj = t & 63, tg = t >> 6;
    __shared__ float Wqs[64][65], Wks[64][65], Wvs[64][65];
    __shared__ float As[4][64];
    for (int u = 0; u < 16; ++u) {
        int idx = t + 256 * u;
        int o = idx >> 6, d = idx & 63;
        Wqs[d][o] = Wq[(h * 64 + o) * 64 + d];
        Wks[d][o] = Wk[(h * 64 + o) * 64 + d];
        Wvs[d][o] = Wv[(h * 64 + o) * 64 + d];
    }
    float bqv = bq[h * 64 + tj], bkv = bk[h * 64 + tj], bvv = bv[h * 64 + tj];
    __syncthreads();
    for (int it = 0; it < 65; ++it) {
        int s = it * 4 + tg;
        bool valid = s < S_LEN;
        int sv = valid ? s : S_LEN - 1;
        As[tg][tj] = xln[((size_t)n * S_LEN + sv) * 768 + h * 64 + tj];
        __syncthreads();
        float aq = 0, ak = 0, av = 0;
#pragma unroll
        for (int d = 0; d < 64; ++d) {
            float a = As[tg][d];
            aq += a * Wqs[d][tj];
            ak += a * Wks[d][tj];
            av += a * Wvs[d][tj];
        }
        if (valid) {
            size_t base = (((size_t)n * S_LEN + s) * H_HEADS + h) * 64 + tj;
            q[base] = (aq + bqv) * 0.125f;
            k[base] = ak + bkv;
            v[base] = av + bvv;
        }
        __syncthreads();
    }
}

// ---------------- flash attention: block = (n, h, 32 q-rows), K/V tiles in LDS ----------------
__global__ __launch_bounds__(256) void attn_flash(const float* __restrict__ q,
                                                  const float* __restrict__ k,
                                                  const float* __restrict__ v,
                                                  float* __restrict__ tok) {
    __shared__ float Qs[32][64];
    __shared__ float Ks[64][65];
    __shared__ float Vs[64][64];
    __shared__ float Ps[32][64];
    int b = blockIdx.x;
    int qg = b % 9;
    int nh = b / 9;
    int h = nh % H_HEADS, n = nh / H_HEADS;
    int t = threadIdx.x, w = t >> 6, lane = t & 63;
    {
        int r = t >> 3;
        int c = (t & 7) * 8;
        int qrow = qg * 32 + r; if (qrow > 256) qrow = 256;
        const float* src = q + (((size_t)n * S_LEN + qrow) * H_HEADS + h) * 64 + c;
        float4 a = *(const float4*)src;
        float4 bq4 = *(const float4*)(src + 4);
        *(float4*)&Qs[r][c] = a;
        *(float4*)&Qs[r][c + 4] = bq4;
    }
    float mr[8], lr[8], acc[8];
#pragma unroll
    for (int r = 0; r < 8; ++r) { mr[r] = -INFINITY; lr[r] = 0.f; acc[r] = 0.f; }
    __syncthreads();
    const float* kbase = k + ((size_t)n * S_LEN * H_HEADS + h) * 64;
    const float* vbase = v + ((size_t)n * S_LEN * H_HEADS + h) * 64;
    for (int kt = 0; kt < 5; ++kt) {
        int kb0 = kt * 64;
        int len = S_LEN - kb0; if (len > 64) len = 64;
        {
            int r = t >> 2, c = (t & 3) * 16;
            int kr = (r < len) ? (kb0 + r) : kb0;
            const float* ks = kbase + (size_t)kr * 768 + c;
            const float* vs = vbase + (size_t)kr * 768 + c;
#pragma unroll
            for (int j = 0; j < 4; ++j) {
                float4 kv = *(const float4*)(ks + j * 4);
                Ks[r][c + j * 4 + 0] = kv.x; Ks[r][c + j * 4 + 1] = kv.y;
                Ks[r][c + j * 4 + 2] = kv.z; Ks[r][c + j * 4 + 3] = kv.w;
                *(float4*)&Vs[r][c + j * 4] = *(const float4*)(vs + j * 4);
            }
        }
        __syncthreads();
        bool kvalid = lane < len;
#pragma unroll
        for (int r = 0; r < 8; ++r) {
            int qr = w * 8 + r;
            float s = 0.f;
#pragma unroll
            for (int d4 = 0; d4 < 16; ++d4) {
                float4 qv = *(float4*)&Qs[qr][d4 * 4];
                s += qv.x * Ks[lane][d4 * 4 + 0] + qv.y * Ks[lane][d4 * 4 + 1]
                   + qv.z * Ks[lane][d4 * 4 + 2] + qv.w * Ks[lane][d4 * 4 + 3];
            }
            s = kvalid ? s : -INFINITY;
            float wm = s;
            for (int o = 32; o; o >>= 1) wm = fmaxf(wm, __shfl_xor(wm, o));
            float mn = fmaxf(mr[r], wm);
            float e = kvalid ? expf(s - mn) : 0.f;
            Ps[qr][lane] = e;
            float wsum = e;
            for (int o = 32; o; o >>= 1) wsum += __shfl_xor(wsum, o);
            float scale = expf(mr[r] - mn);
            lr[r] = lr[r] * scale + wsum;
            mr[r] = mn;
            float pv = 0.f;
#pragma unroll
            for (int k4 = 0; k4 < 16; ++k4) {
                float4 p4 = *(float4*)&Ps[qr][k4 * 4];
                pv += p4.x * Vs[k4 * 4 + 0][lane] + p4.y * Vs[k4 * 4 + 1][lane]
                    + p4.z * Vs[k4 * 4 + 2][lane] + p4.w * Vs[k4 * 4 + 3][lane];
            }
            acc[r] = acc[r] * scale + pv;
        }
        __syncthreads();
    }
#pragma unroll
    for (int r = 0; r < 8; ++r) {
        int qrow = qg * 32 + w * 8 + r;
        if (qrow < S_LEN) {
            float o = acc[r] / lr[r];
            tok[((size_t)n * S_LEN + qrow) * 768 + h * 64 + lane] += o;
        }
    }
}

// ---------------- fp32 -> bf16 strided conversion ----------------
__global__ __launch_bounds__(256) void f32_to_bf16(const float* __restrict__ in,
                                                   ushort_t* __restrict__ out,
                                                   int cols, int ld, int total) {
    int idx = (blockIdx.x * 256 + threadIdx.x) * 4;
    if (idx >= total) return;
    int r = idx / cols, c = idx % cols;
    float4 v = *(const float4*)(in + (size_t)r * ld + c);
    out[idx + 0] = f2bf(v.x); out[idx + 1] = f2bf(v.y);
    out[idx + 2] = f2bf(v.z); out[idx + 3] = f2bf(v.w);
}

// ---------------- bf16 MFMA GEMM: C = op(A @ B^T), 128x128 tile, BK=32 ----------------
__device__ __forceinline__ float gelu_exact(float x) {
    return 0.5f * x * (1.0f + erff(x * 0.70710678118654752f));
}

// MODE 0: bias + gelu -> bf16 out.  MODE 1: (+bias) + accumulate fp32 out.
template <int MODE>
__global__ __launch_bounds__(256) void mfma_gemm(const ushort_t* __restrict__ A,
                                                 const ushort_t* __restrict__ B,
                                                 const float* __restrict__ bias,
                                                 void* __restrict__ Cv,
                                                 int K, int lda, int ldb, int ldc) {
    __shared__ ushort_t As[128 * 32];
    __shared__ ushort_t Bs[128 * 32];
    int t = threadIdx.x;
    int lane = t & 63, wid = t >> 6;
    int wr = wid >> 1, wc = wid & 1;
    int bm = blockIdx.y, bn = blockIdx.x;
    const ushort_t* Ag = A + (size_t)(bm * 128) * lda;
    const ushort_t* Bg = B + (size_t)(bn * 128) * ldb;
    int srow = t >> 2, scol = (t & 3) * 8;
    int frow = lane & 15, fk = (lane >> 4) * 8;
    f32x4 acc[4][4];
#pragma unroll
    for (int m = 0; m < 4; ++m)
#pragma unroll
        for (int n = 0; n < 4; ++n) acc[m][n] = (f32x4){0.f, 0.f, 0.f, 0.f};
    for (int k0 = 0; k0 < K; k0 += 32) {
        short8 a0 = *(const short8*)(Ag + (size_t)srow * lda + k0 + scol);
        short8 a1 = *(const short8*)(Ag + (size_t)(srow + 64) * lda + k0 + scol);
        short8 b0 = *(const short8*)(Bg + (size_t)srow * ldb + k0 + scol);
        short8 b1 = *(const short8*)(Bg + (size_t)(srow + 64) * ldb + k0 + scol);
        __syncthreads();
        *(short8*)&As[t * 8] = a0;
        *(short8*)&As[2048 + t * 8] = a1;
        *(short8*)&Bs[t * 8] = b0;
        *(short8*)&Bs[2048 + t * 8] = b1;
        __syncthreads();
        short8 af[4], bfr[4];
#pragma unroll
        for (int m = 0; m < 4; ++m) af[m] = *(short8*)&As[(wr * 64 + m * 16 + frow) * 32 + fk];
#pragma unroll
        for (int n = 0; n < 4; ++n) bfr[n] = *(short8*)&Bs[(wc * 64 + n * 16 + frow) * 32 + fk];
#pragma unroll
        for (int m = 0; m < 4; ++m)
#pragma unroll
            for (int n = 0; n < 4; ++n)
                acc[m][n] = __builtin_amdgcn_mfma_f32_16x16x32_bf16(af[m], bfr[n], acc[m][n], 0, 0, 0);
    }
    int rowbase = bm * 128 + wr * 64 + ((lane >> 4) * 4);
    int colbase = bn * 128 + wc * 64 + (lane & 15);
#pragma unroll
    for (int n = 0; n < 4; ++n) {
        int col = colbase + n * 16;
        float bv = bias ? bias[col] : 0.f;
#pragma unroll
        for (int m = 0; m < 4; ++m) {
            int row0 = rowbase + m * 16;
#pragma unroll
            for (int j = 0; j < 4; ++j) {
                float val = acc[m][n][j] + bv;
                if (MODE == 0) {
                    ((ushort_t*)Cv)[(size_t)(row0 + j) * ldc + col] = f2bf(gelu_exact(val));
                } else {
                    float* cp = (float*)Cv + (size_t)(row0 + j) * ldc + col;
                    *cp += val;
                }
            }
        }
    }
}

// ---------------- classifier head + softmax ----------------
__global__ __launch_bounds__(64) void head_kernel(const float* __restrict__ tok,
                                                  const float* __restrict__ Whead,
                                                  const float* __restrict__ bhead,
                                                  float* __restrict__ out) {
    int n = blockIdx.x;
    int t = threadIdx.x;
    __shared__ float logits[OUT_DIM];
    if (t < OUT_DIM) {
        float acc = bhead[t];
        const float* xr = tok + (size_t)n * S_LEN * 768;
        const float* w = Whead + t * 768;
        for (int d = 0; d < 768; ++d) acc += xr[d] * w[d];
        logits[t] = acc;
    }
    __syncthreads();
    if (t == 0) {
        float m = -INFINITY;
        for (int o = 0; o < OUT_DIM; ++o) m = fmaxf(m, logits[o]);
        float ssum = 0.f;
        float e[OUT_DIM];
        for (int o = 0; o < OUT_DIM; ++o) { e[o] = expf(logits[o] - m); ssum += e[o]; }
        float inv = 1.0f / ssum;
        for (int o = 0; o < OUT_DIM; ++o) out[n * OUT_DIM + o] = e[o] * inv;
    }
}

extern "C" void kernel_launch(void* const* d_in, const int* in_sizes, int n_in,
                              void* d_out, int out_size, void* d_ws, size_t ws_size,
                              hipStream_t stream) {
    const float* images = (const float*)d_in[0];
    const float* Wemb   = (const float*)d_in[1];
    const float* bemb   = (const float*)d_in[2];
    const float* cls    = (const float*)d_in[3];
    const float* Wq     = (const float*)d_in[4];
    const float* bq     = (const float*)d_in[5];
    const float* Wk     = (const float*)d_in[6];
    const float* bk     = (const float*)d_in[7];
    const float* Wv     = (const float*)d_in[8];
    const float* bv     = (const float*)d_in[9];
    const float* ln1_g  = (const float*)d_in[10];
    const float* ln1_b  = (const float*)d_in[11];
    const float* ln2_g  = (const float*)d_in[12];
    const float* ln2_b  = (const float*)d_in[13];
    const float* W1     = (const float*)d_in[14];
    const float* b1     = (const float*)d_in[15];
    const float* W2     = (const float*)d_in[16];
    const float* b2     = (const float*)d_in[17];
    const float* Whead  = (const float*)d_in[18];
    const float* bhead  = (const float*)d_in[19];
    float* out = (float*)d_out;

    const size_t TOK = (size_t)R_ROWS * D_MODEL;        // 12,632,064
    const size_t TOKP = (size_t)R_PAD * D_MODEL;        // 12,681,216
    float* ws   = (float*)d_ws;
    float* pos  = ws;                                   // 197,376
    float* tok  = pos + 197376;                         // TOKP (padded)
    float* xln  = tok + TOKP;                           // TOK fp32
    ushort_t* xbf = (ushort_t*)(xln + TOK);             // TOKP ushorts
    float* qb   = xln + TOK + TOKP / 2;                 // TOK
    float* kb   = qb + TOK;
    float* vb   = kb + TOK;
    ushort_t* w1bf = (ushort_t*)(vb + TOK);             // 1536*768 ushorts
    ushort_t* w2bf = w1bf + 1536 * 768;                 // 768*1536 ushorts
    ushort_t* hid  = (ushort_t*)qb;                     // overlay: R_PAD*1536 ushorts (q/k dead)

    pos_kernel<<<S_LEN, 256, 0, stream>>>(pos);
    embed_kernel<<<R_ROWS, 256, 0, stream>>>(images, Wemb, bemb, cls, pos, tok);

    for (int l = 0; l < L_LAYERS; ++l) {
        const size_t wqkv_off = (size_t)l * H_HEADS * 64 * 64;
        const size_t bqkv_off = (size_t)l * H_HEADS * 64;
        ln_kernel<false><<<R_ROWS, 256, 0, stream>>>(tok, ln1_g + l * 768, ln1_b + l * 768, xln);
        qkv_kernel<<<N_IMG * H_HEADS, 256, 0, stream>>>(
            xln, Wq + wqkv_off, bq + bqkv_off, Wk + wqkv_off, bk + bqkv_off,
            Wv + wqkv_off, bv + bqkv_off, qb, kb, vb);
        attn_flash<<<N_IMG * H_HEADS * 9, 256, 0, stream>>>(qb, kb, vb, tok);
        ln_kernel<true><<<R_ROWS, 256, 0, stream>>>(tok, ln2_g + l * 768, ln2_b + l * 768, xbf);
        for (int c = 0; c < 2; ++c) {
            int c0 = c * F_CHUNK;
            f32_to_bf16<<<1152, 256, 0, stream>>>(
                W1 + (size_t)l * F_HID * D_MODEL + (size_t)c0 * D_MODEL, w1bf,
                768, 768, F_CHUNK * 768);
            f32_to_bf16<<<1152, 256, 0, stream>>>(
                W2 + (size_t)l * D_MODEL * F_HID + c0, w2bf,
                F_CHUNK, F_HID, 768 * F_CHUNK);
            mfma_gemm<0><<<dim3(F_CHUNK / 128, R_PAD / 128), 256, 0, stream>>>(
                xbf, w1bf, b1 + (size_t)l * F_HID + c0, hid, 768, 768, 768, F_CHUNK);
            mfma_gemm<1><<<dim3(D_MODEL / 128, R_PAD / 128), 256, 0, stream>>>(
                hid, w2bf, (c == 0) ? (b2 + (size_t)l * D_MODEL) : (const float*)nullptr,
                tok, F_CHUNK, F_CHUNK, F_CHUNK, D_MODEL);
        }
    }
    head_kernel<<<N_IMG, 64, 0, stream>>>(tok, Whead, bhead, out);
}

// Round 3
// 10488.375 us; speedup vs baseline: 10.1354x; 3.4092x over previous
//
#include <hip/hip_runtime.h>
#include <math.h>

#define N_IMG 64
#define S_LEN 257
#define D_MODEL 768
#define H_HEADS 12
#define L_LAYERS 12
#define F_HID 3072
#define F_CHUNK 1536
#define OUT_DIM 10
#define R_ROWS (N_IMG * S_LEN)   // 16448
#define R_PAD 16512              // 129 * 128
#define SKV 320                  // padded key count for vT

typedef unsigned short ushort_t;
typedef __attribute__((ext_vector_type(4))) float f32x4;
typedef __attribute__((ext_vector_type(8))) short short8;
typedef __attribute__((ext_vector_type(2))) unsigned int u32x2;

__device__ __forceinline__ ushort_t f2bf(float x) {
    unsigned u = __float_as_uint(x);
    u += 0x7fffu + ((u >> 16) & 1u);
    return (ushort_t)(u >> 16);
}
__device__ __forceinline__ float bf2f(ushort_t u) {
    return __uint_as_float(((unsigned)u) << 16);
}

// ---------------- positional embedding (double precision, matches numpy f64) ----------------
__global__ __launch_bounds__(256) void pos_kernel(float* __restrict__ pos) {
    int i = blockIdx.x;
    int t = threadIdx.x;
    for (int u = 0; u < 3; ++u) {
        int j = t + 256 * u;
        double e = (double)(j & ~1) / 768.0;
        double angle = (double)i * exp(-e * 9.210340371976184);
        double v = (j & 1) ? cos(angle) : sin(angle);
        pos[i * 768 + j] = (float)v;
    }
}

// ---------------- patch embed + cls + pos ----------------
__global__ __launch_bounds__(256) void embed_kernel(const float* __restrict__ images,
                                                    const float* __restrict__ Wemb,
                                                    const float* __restrict__ bemb,
                                                    const float* __restrict__ cls,
                                                    const float* __restrict__ pos,
                                                    float* __restrict__ tok) {
    int b = blockIdx.x;
    int n = b / S_LEN, s = b % S_LEN;
    int t = threadIdx.x;
    __shared__ float p[16];
    if (s > 0 && t < 16) p[t] = images[n * 4096 + (s - 1) * 16 + t];
    __syncthreads();
    for (int u = 0; u < 3; ++u) {
        int d = t + 256 * u;
        float acc;
        if (s == 0) {
            acc = cls[d];
        } else {
            acc = bemb[d];
            const float4* w = (const float4*)(Wemb + d * 16);
            float4 w0 = w[0], w1 = w[1], w2 = w[2], w3 = w[3];
            acc += p[0] * w0.x + p[1] * w0.y + p[2] * w0.z + p[3] * w0.w;
            acc += p[4] * w1.x + p[5] * w1.y + p[6] * w1.z + p[7] * w1.w;
            acc += p[8] * w2.x + p[9] * w2.y + p[10] * w2.z + p[11] * w2.w;
            acc += p[12] * w3.x + p[13] * w3.y + p[14] * w3.z + p[15] * w3.w;
        }
        tok[(size_t)b * 768 + d] = acc + pos[s * 768 + d];
    }
}

// ---------------- layernorm: fp32 or bf16 output ----------------
template <bool BF>
__global__ __launch_bounds__(256) void ln_kernel(const float* __restrict__ x,
                                                 const float* __restrict__ g,
                                                 const float* __restrict__ b,
                                                 void* __restrict__ y) {
    int row = blockIdx.x;
    int t = threadIdx.x;
    const float* xr = x + (size_t)row * 768;
    float v0 = xr[t], v1 = xr[t + 256], v2 = xr[t + 512];
    float s = v0 + v1 + v2;
    float sq = v0 * v0 + v1 * v1 + v2 * v2;
    for (int o = 32; o; o >>= 1) {
        s += __shfl_xor(s, o);
        sq += __shfl_xor(sq, o);
    }
    __shared__ float red[8];
    if ((t & 63) == 0) { red[(t >> 6) * 2] = s; red[(t >> 6) * 2 + 1] = sq; }
    __syncthreads();
    float ts = red[0] + red[2] + red[4] + red[6];
    float tq = red[1] + red[3] + red[5] + red[7];
    float mu = ts * (1.0f / 768.0f);
    float var = tq * (1.0f / 768.0f) - mu * mu;
    float rs = rsqrtf(var + 1e-5f);
    float o0 = (v0 - mu) * rs * g[t] + b[t];
    float o1 = (v1 - mu) * rs * g[t + 256] + b[t + 256];
    float o2 = (v2 - mu) * rs * g[t + 512] + b[t + 512];
    if (BF) {
        ushort_t* yr = (ushort_t*)y + (size_t)row * 768;
        yr[t] = f2bf(o0); yr[t + 256] = f2bf(o1); yr[t + 512] = f2bf(o2);
    } else {
        float* yr = (float*)y + (size_t)row * 768;
        yr[t] = o0; yr[t + 256] = o1; yr[t + 512] = o2;
    }
}

// ---------------- fused QKV: one block per (n, h); emits hi/lo bf16 Q,K and transposed bf16 V ----
__global__ __launch_bounds__(256) void qkv_kernel(const float* __restrict__ xln,
                                                  const float* __restrict__ Wq, const float* __restrict__ bq,
                                                  const float* __restrict__ Wk, const float* __restrict__ bk,
                                                  const float* __restrict__ Wv, const float* __restrict__ bv,
                                                  ushort_t* __restrict__ qhb, ushort_t* __restrict__ qlb,
                                                  ushort_t* __restrict__ khb, ushort_t* __restrict__ klb,
                                                  ushort_t* __restrict__ vtb) {
    int nh = blockIdx.x;
    int h = nh % H_HEADS, n = nh / H_HEADS;
    int t = threadIdx.x;
    int tj = t & 63, tg = t >> 6;
    __shared__ float Wqs[64][65], Wks[64][65], Wvs[64][65];
    __shared__ float As[2][4][64];
    __shared__ ushort_t vstage[64][66];
    for (int u = 0; u < 16; ++u) {
        int idx = t + 256 * u;
        int o = idx >> 6, d = idx & 63;
        Wqs[d][o] = Wq[(h * 64 + o) * 64 + d];
        Wks[d][o] = Wk[(h * 64 + o) * 64 + d];
        Wvs[d][o] = Wv[(h * 64 + o) * 64 + d];
    }
    float bqv = bq[h * 64 + tj], bkv = bk[h * 64 + tj], bvv = bv[h * 64 + tj];
    __syncthreads();
    const size_t hqk = ((size_t)n * H_HEADS + h) * (S_LEN * 64);
    ushort_t* vdst_head = vtb + ((size_t)n * H_HEADS + h) * (64 * SKV);
    for (int it = 0; it < 80; ++it) {
        int s = it * 4 + tg;
        bool valid = s < S_LEN;
        int sv = valid ? s : S_LEN - 1;
        As[it & 1][tg][tj] = xln[((size_t)n * S_LEN + sv) * 768 + h * 64 + tj];
        float aq = 0.f, ak = 0.f, av = 0.f;
#pragma unroll
        for (int d = 0; d < 64; ++d) {
            float a = As[it & 1][tg][d];
            aq += a * Wqs[d][tj];
            ak += a * Wks[d][tj];
            av += a * Wvs[d][tj];
        }
        if (valid) {
            size_t base = hqk + (size_t)s * 64 + tj;
            float qs = (aq + bqv) * 0.125f;   // pre-apply 1/sqrt(64)
            ushort_t qhv = f2bf(qs);
            qhb[base] = qhv;
            qlb[base] = f2bf(qs - bf2f(qhv));
            float ks = ak + bkv;
            ushort_t khv = f2bf(ks);
            khb[base] = khv;
            klb[base] = f2bf(ks - bf2f(khv));
        }
        vstage[s & 63][tj] = f2bf(valid ? (av + bvv) : 0.f);
        if ((it & 15) == 15) {
            __syncthreads();
            int s0 = (it >> 4) * 64;
            int d = t >> 2, sc0 = (t & 3) * 16;
            ushort_t tmp[16];
#pragma unroll
            for (int i = 0; i < 16; ++i) tmp[i] = vstage[sc0 + i][d];
            ushort_t* dst = vdst_head + (size_t)d * SKV + s0 + sc0;
            *(short8*)dst = *(short8*)&tmp[0];
            *(short8*)(dst + 8) = *(short8*)&tmp[8];
            __syncthreads();
        }
    }
}

// ---------------- MFMA flash attention ----------------
// block = (n, h, 64 q-rows) as 4 waves x 16 q-rows. Swapped QK^T (mfma(K,Q)) so the
// key axis is register-local; hi/lo bf16 for scores; P -> bf16 via XOR-swizzled
// per-wave LDS; PV with V^T fragments loaded directly from global. No barriers.
__global__ __launch_bounds__(256) void attn_mfma(const ushort_t* __restrict__ qh,
                                                 const ushort_t* __restrict__ ql,
                                                 const ushort_t* __restrict__ kh,
                                                 const ushort_t* __restrict__ kl,
                                                 const ushort_t* __restrict__ vT,
                                                 float* __restrict__ tok) {
    __shared__ ushort_t Plds[4][1024];   // 2KB per wave
    int b = blockIdx.x;
    int qt = b % 5;
    int nh = b / 5;
    int h = nh % H_HEADS, n = nh / H_HEADS;
    int t = threadIdx.x, w = t >> 6, lane = t & 63;
    int lq = lane & 15, g = lane >> 4;
    const size_t hoff = ((size_t)n * H_HEADS + h) * (S_LEN * 64);
    const ushort_t* qhp = qh + hoff;
    const ushort_t* qlp = ql + hoff;
    const ushort_t* khp = kh + hoff;
    const ushort_t* klp = kl + hoff;
    const ushort_t* vp  = vT + ((size_t)n * H_HEADS + h) * (64 * SKV);
    char* pwave = (char*)&Plds[w][0];
    const int xorm = (lq & 7) << 4;

    int qrow = qt * 64 + w * 16 + lq;
    int qcl = qrow > 256 ? 256 : qrow;
    short8 qfh[2], qfl[2];
#pragma unroll
    for (int kk = 0; kk < 2; ++kk) {
        qfh[kk] = *(const short8*)(qhp + (size_t)qcl * 64 + kk * 32 + g * 8);
        qfl[kk] = *(const short8*)(qlp + (size_t)qcl * 64 + kk * 32 + g * 8);
    }
    float m = -INFINITY, lsum = 0.f;
    f32x4 o[4];
#pragma unroll
    for (int dt = 0; dt < 4; ++dt) o[dt] = (f32x4){0.f, 0.f, 0.f, 0.f};

    for (int kt = 0; kt < 5; ++kt) {
        // ---- QK^T (swapped): C[key][q], lane holds q=lq, keys (g*4+j) per 16-subtile ----
        f32x4 c[4];
#pragma unroll
        for (int st = 0; st < 4; ++st) {
            int key = kt * 64 + st * 16 + lq;
            int kcl = key > 256 ? 256 : key;
            const ushort_t* krh = khp + (size_t)kcl * 64 + g * 8;
            const ushort_t* krl = klp + (size_t)kcl * 64 + g * 8;
            c[st] = (f32x4){0.f, 0.f, 0.f, 0.f};
#pragma unroll
            for (int kk = 0; kk < 2; ++kk) {
                short8 ah = *(const short8*)(krh + kk * 32);
                short8 al = *(const short8*)(krl + kk * 32);
                c[st] = __builtin_amdgcn_mfma_f32_16x16x32_bf16(ah, qfh[kk], c[st], 0, 0, 0);
                c[st] = __builtin_amdgcn_mfma_f32_16x16x32_bf16(ah, qfl[kk], c[st], 0, 0, 0);
                c[st] = __builtin_amdgcn_mfma_f32_16x16x32_bf16(al, qfh[kk], c[st], 0, 0, 0);
            }
        }
        // ---- mask + online softmax (stats per q=lq, replicated over g) ----
        float tmax = -INFINITY;
#pragma unroll
        for (int st = 0; st < 4; ++st)
#pragma unroll
            for (int j = 0; j < 4; ++j) {
                int key = kt * 64 + st * 16 + g * 4 + j;
                float sv = (key <= 256) ? c[st][j] : -INFINITY;
                c[st][j] = sv;
                tmax = fmaxf(tmax, sv);
            }
        tmax = fmaxf(tmax, __shfl_xor(tmax, 16));
        tmax = fmaxf(tmax, __shfl_xor(tmax, 32));
        float mn = fmaxf(m, tmax);
        float scale = __expf(m - mn);
        float psum = 0.f;
        unsigned pw[4][2];
#pragma unroll
        for (int st = 0; st < 4; ++st) {
            float p0 = __expf(c[st][0] - mn), p1 = __expf(c[st][1] - mn);
            float p2 = __expf(c[st][2] - mn), p3 = __expf(c[st][3] - mn);
            psum += (p0 + p1) + (p2 + p3);
            pw[st][0] = (unsigned)f2bf(p0) | ((unsigned)f2bf(p1) << 16);
            pw[st][1] = (unsigned)f2bf(p2) | ((unsigned)f2bf(p3) << 16);
        }
        psum += __shfl_xor(psum, 16);
        psum += __shfl_xor(psum, 32);
        lsum = lsum * scale + psum;
        m = mn;
        // ---- P -> LDS (bf16, XOR-swizzled; per-wave private, no barrier) ----
#pragma unroll
        for (int st = 0; st < 4; ++st) {
            int off = (lq * 128 + st * 32 + g * 8) ^ xorm;
            *(u32x2*)(pwave + off) = (u32x2){pw[st][0], pw[st][1]};
        }
        // ---- rescale O, then PV: C[q][d] ----
        float s0 = __shfl(scale, g * 4 + 0);
        float s1 = __shfl(scale, g * 4 + 1);
        float s2 = __shfl(scale, g * 4 + 2);
        float s3 = __shfl(scale, g * 4 + 3);
#pragma unroll
        for (int dt = 0; dt < 4; ++dt) {
            o[dt][0] *= s0; o[dt][1] *= s1; o[dt][2] *= s2; o[dt][3] *= s3;
        }
#pragma unroll
        for (int kk = 0; kk < 2; ++kk) {
            int roff = (lq * 128 + kk * 64 + g * 16) ^ xorm;
            short8 pf = *(const short8*)(pwave + roff);
#pragma unroll
            for (int dt = 0; dt < 4; ++dt) {
                const ushort_t* vf = vp + (size_t)(dt * 16 + lq) * SKV + kt * 64 + kk * 32 + g * 8;
                o[dt] = __builtin_amdgcn_mfma_f32_16x16x32_bf16(pf, *(const short8*)vf, o[dt], 0, 0, 0);
            }
        }
    }
    // ---- epilogue: normalize and accumulate into residual ----
    float inv[4];
#pragma unroll
    for (int j = 0; j < 4; ++j) inv[j] = 1.0f / __shfl(lsum, g * 4 + j);
    int qbase = qt * 64 + w * 16;
#pragma unroll
    for (int j = 0; j < 4; ++j) {
        int qr = qbase + g * 4 + j;
        if (qr < S_LEN) {
            float* trow = tok + ((size_t)n * S_LEN + qr) * 768 + h * 64 + lq;
            trow[0]  += o[0][j] * inv[j];
            trow[16] += o[1][j] * inv[j];
            trow[32] += o[2][j] * inv[j];
            trow[48] += o[3][j] * inv[j];
        }
    }
}

// ---------------- fp32 -> bf16 strided conversion ----------------
__global__ __launch_bounds__(256) void f32_to_bf16(const float* __restrict__ in,
                                                   ushort_t* __restrict__ out,
                                                   int cols, int ld, int total) {
    int idx = (blockIdx.x * 256 + threadIdx.x) * 4;
    if (idx >= total) return;
    int r = idx / cols, c = idx % cols;
    float4 v = *(const float4*)(in + (size_t)r * ld + c);
    out[idx + 0] = f2bf(v.x); out[idx + 1] = f2bf(v.y);
    out[idx + 2] = f2bf(v.z); out[idx + 3] = f2bf(v.w);
}

// ---------------- bf16 MFMA GEMM: C = op(A @ B^T), 128x128 tile, BK=32 ----------------
__device__ __forceinline__ float gelu_exact(float x) {
    return 0.5f * x * (1.0f + erff(x * 0.70710678118654752f));
}

// MODE 0: bias + gelu -> bf16 out.  MODE 1: (+bias) + accumulate fp32 out.
template <int MODE>
__global__ __launch_bounds__(256) void mfma_gemm(const ushort_t* __restrict__ A,
                                                 const ushort_t* __restrict__ B,
                                                 const float* __restrict__ bias,
                                                 void* __restrict__ Cv,
                                                 int K, int lda, int ldb, int ldc) {
    __shared__ ushort_t As[128 * 32];
    __shared__ ushort_t Bs[128 * 32];
    int t = threadIdx.x;
    int lane = t & 63, wid = t >> 6;
    int wr = wid >> 1, wc = wid & 1;
    int bm = blockIdx.y, bn = blockIdx.x;
    const ushort_t* Ag = A + (size_t)(bm * 128) * lda;
    const ushort_t* Bg = B + (size_t)(bn * 128) * ldb;
    int srow = t >> 2, scol = (t & 3) * 8;
    int frow = lane & 15, fk = (lane >> 4) * 8;
    f32x4 acc[4][4];
#pragma unroll
    for (int m = 0; m < 4; ++m)
#pragma unroll
        for (int n = 0; n < 4; ++n) acc[m][n] = (f32x4){0.f, 0.f, 0.f, 0.f};
    for (int k0 = 0; k0 < K; k0 += 32) {
        short8 a0 = *(const short8*)(Ag + (size_t)srow * lda + k0 + scol);
        short8 a1 = *(const short8*)(Ag + (size_t)(srow + 64) * lda + k0 + scol);
        short8 b0 = *(const short8*)(Bg + (size_t)srow * ldb + k0 + scol);
        short8 b1 = *(const short8*)(Bg + (size_t)(srow + 64) * ldb + k0 + scol);
        __syncthreads();
        *(short8*)&As[t * 8] = a0;
        *(short8*)&As[2048 + t * 8] = a1;
        *(short8*)&Bs[t * 8] = b0;
        *(short8*)&Bs[2048 + t * 8] = b1;
        __syncthreads();
        short8 af[4], bfr[4];
#pragma unroll
        for (int m = 0; m < 4; ++m) af[m] = *(short8*)&As[(wr * 64 + m * 16 + frow) * 32 + fk];
#pragma unroll
        for (int n = 0; n < 4; ++n) bfr[n] = *(short8*)&Bs[(wc * 64 + n * 16 + frow) * 32 + fk];
#pragma unroll
        for (int m = 0; m < 4; ++m)
#pragma unroll
            for (int n = 0; n < 4; ++n)
                acc[m][n] = __builtin_amdgcn_mfma_f32_16x16x32_bf16(af[m], bfr[n], acc[m][n], 0, 0, 0);
    }
    int rowbase = bm * 128 + wr * 64 + ((lane >> 4) * 4);
    int colbase = bn * 128 + wc * 64 + (lane & 15);
#pragma unroll
    for (int n = 0; n < 4; ++n) {
        int col = colbase + n * 16;
        float bv = bias ? bias[col] : 0.f;
#pragma unroll
        for (int m = 0; m < 4; ++m) {
            int row0 = rowbase + m * 16;
#pragma unroll
            for (int j = 0; j < 4; ++j) {
                float val = acc[m][n][j] + bv;
                if (MODE == 0) {
                    ((ushort_t*)Cv)[(size_t)(row0 + j) * ldc + col] = f2bf(gelu_exact(val));
                } else {
                    float* cp = (float*)Cv + (size_t)(row0 + j) * ldc + col;
                    *cp += val;
                }
            }
        }
    }
}

// ---------------- classifier head + softmax ----------------
__global__ __launch_bounds__(64) void head_kernel(const float* __restrict__ tok,
                                                  const float* __restrict__ Whead,
                                                  const float* __restrict__ bhead,
                                                  float* __restrict__ out) {
    int n = blockIdx.x;
    int t = threadIdx.x;
    __shared__ float logits[OUT_DIM];
    if (t < OUT_DIM) {
        float acc = bhead[t];
        const float* xr = tok + (size_t)n * S_LEN * 768;
        const float* w = Whead + t * 768;
        for (int d = 0; d < 768; ++d) acc += xr[d] * w[d];
        logits[t] = acc;
    }
    __syncthreads();
    if (t == 0) {
        float m = -INFINITY;
        for (int o = 0; o < OUT_DIM; ++o) m = fmaxf(m, logits[o]);
        float ssum = 0.f;
        float e[OUT_DIM];
        for (int o = 0; o < OUT_DIM; ++o) { e[o] = expf(logits[o] - m); ssum += e[o]; }
        float inv = 1.0f / ssum;
        for (int o = 0; o < OUT_DIM; ++o) out[n * OUT_DIM + o] = e[o] * inv;
    }
}

extern "C" void kernel_launch(void* const* d_in, const int* in_sizes, int n_in,
                              void* d_out, int out_size, void* d_ws, size_t ws_size,
                              hipStream_t stream) {
    const float* images = (const float*)d_in[0];
    const float* Wemb   = (const float*)d_in[1];
    const float* bemb   = (const float*)d_in[2];
    const float* cls    = (const float*)d_in[3];
    const float* Wq     = (const float*)d_in[4];
    const float* bq     = (const float*)d_in[5];
    const float* Wk     = (const float*)d_in[6];
    const float* bk     = (const float*)d_in[7];
    const float* Wv     = (const float*)d_in[8];
    const float* bv     = (const float*)d_in[9];
    const float* ln1_g  = (const float*)d_in[10];
    const float* ln1_b  = (const float*)d_in[11];
    const float* ln2_g  = (const float*)d_in[12];
    const float* ln2_b  = (const float*)d_in[13];
    const float* W1     = (const float*)d_in[14];
    const float* b1     = (const float*)d_in[15];
    const float* W2     = (const float*)d_in[16];
    const float* b2     = (const float*)d_in[17];
    const float* Whead  = (const float*)d_in[18];
    const float* bhead  = (const float*)d_in[19];
    float* out = (float*)d_out;

    const size_t TOK  = (size_t)R_ROWS * D_MODEL;          // 12,632,064
    const size_t TOKP = (size_t)R_PAD * D_MODEL;           // 12,681,216
    const size_t QKSZ = (size_t)N_IMG * H_HEADS * S_LEN * 64;  // 12,632,064
    const size_t VTSZ = (size_t)N_IMG * H_HEADS * 64 * SKV;    // 15,728,640
    float* ws   = (float*)d_ws;
    float* pos  = ws;                                      // 197,376 f32
    float* tok  = pos + 197376;                            // TOKP f32
    float* xln  = tok + TOKP;                              // TOK f32
    ushort_t* xbf  = (ushort_t*)(xln + TOK);               // TOKP bf16
    ushort_t* qhb  = xbf + TOKP;                           // QKSZ bf16 each
    ushort_t* qlb  = qhb + QKSZ;
    ushort_t* khb  = qlb + QKSZ;
    ushort_t* klb  = khb + QKSZ;
    ushort_t* vtb  = klb + QKSZ;                           // VTSZ bf16
    ushort_t* w1bf = vtb + VTSZ;                           // 1536*768
    ushort_t* w2bf = w1bf + (size_t)F_CHUNK * D_MODEL;     // 768*1536
    ushort_t* hid  = qhb;  // overlay: R_PAD*1536 bf16 (25.4M) fits in qh..kl (50.5M)

    pos_kernel<<<S_LEN, 256, 0, stream>>>(pos);
    embed_kernel<<<R_ROWS, 256, 0, stream>>>(images, Wemb, bemb, cls, pos, tok);

    for (int l = 0; l < L_LAYERS; ++l) {
        const size_t wqkv_off = (size_t)l * H_HEADS * 64 * 64;
        const size_t bqkv_off = (size_t)l * H_HEADS * 64;
        ln_kernel<false><<<R_ROWS, 256, 0, stream>>>(tok, ln1_g + l * 768, ln1_b + l * 768, xln);
        qkv_kernel<<<N_IMG * H_HEADS, 256, 0, stream>>>(
            xln, Wq + wqkv_off, bq + bqkv_off, Wk + wqkv_off, bk + bqkv_off,
            Wv + wqkv_off, bv + bqkv_off, qhb, qlb, khb, klb, vtb);
        attn_mfma<<<N_IMG * H_HEADS * 5, 256, 0, stream>>>(qhb, qlb, khb, klb, vtb, tok);
        ln_kernel<true><<<R_ROWS, 256, 0, stream>>>(tok, ln2_g + l * 768, ln2_b + l * 768, xbf);
        for (int c = 0; c < 2; ++c) {
            int c0 = c * F_CHUNK;
            f32_to_bf16<<<1152, 256, 0, stream>>>(
                W1 + (size_t)l * F_HID * D_MODEL + (size_t)c0 * D_MODEL, w1bf,
                768, 768, F_CHUNK * 768);
            f32_to_bf16<<<1152, 256, 0, stream>>>(
                W2 + (size_t)l * D_MODEL * F_HID + c0, w2bf,
                F_CHUNK, F_HID, 768 * F_CHUNK);
            mfma_gemm<0><<<dim3(F_CHUNK / 128, R_PAD / 128), 256, 0, stream>>>(
                xbf, w1bf, b1 + (size_t)l * F_HID + c0, hid, 768, 768, 768, F_CHUNK);
            mfma_gemm<1><<<dim3(D_MODEL / 128, R_PAD / 128), 256, 0, stream>>>(
                hid, w2bf, (c == 0) ? (b2 + (size_t)l * D_MODEL) : (const float*)nullptr,
                tok, F_CHUNK, F_CHUNK, F_CHUNK, D_MODEL);
        }
    }
    head_kernel<<<N_IMG, 64, 0, stream>>>(tok, Whead, bhead, out);
}

// Round 4
// 7549.738 us; speedup vs baseline: 14.0805x; 1.3892x over previous
//
#include <hip/hip_runtime.h>
#include <math.h>
#include <stdint.h>

#define N_IMG 64
#define S_LEN 257
#define D_MODEL 768
#define H_HEADS 12
#define L_LAYERS 12
#define F_HID 3072
#define F_CHUNK 1536
#define OUT_DIM 10
#define R_ROWS (N_IMG * S_LEN)   // 16448
#define R_PAD 16512              // 129 * 128
#define SKV 320                  // padded key count for vT

typedef unsigned short ushort_t;
typedef __attribute__((ext_vector_type(4))) float f32x4;
typedef __attribute__((ext_vector_type(8))) short short8;
typedef __attribute__((ext_vector_type(2))) unsigned int u32x2;

__device__ __forceinline__ ushort_t f2bf(float x) {
    unsigned u = __float_as_uint(x);
    u += 0x7fffu + ((u >> 16) & 1u);
    return (ushort_t)(u >> 16);
}

// async global->LDS, 16B per lane; dest = wave-uniform base + lane*16 (CK-style casts)
__device__ __forceinline__ void glds16(const ushort_t* g, const ushort_t* l) {
    __builtin_amdgcn_global_load_lds(
        (const __attribute__((address_space(1))) unsigned int*)(uintptr_t)g,
        (__attribute__((address_space(3))) unsigned int*)(uintptr_t)l,
        16, 0, 0);
}

// ---------------- positional embedding (double precision, matches numpy f64) ----------------
__global__ __launch_bounds__(256) void pos_kernel(float* __restrict__ pos) {
    int i = blockIdx.x;
    int t = threadIdx.x;
    for (int u = 0; u < 3; ++u) {
        int j = t + 256 * u;
        double e = (double)(j & ~1) / 768.0;
        double angle = (double)i * exp(-e * 9.210340371976184);
        double v = (j & 1) ? cos(angle) : sin(angle);
        pos[i * 768 + j] = (float)v;
    }
}

// ---------------- patch embed + cls + pos ----------------
__global__ __launch_bounds__(256) void embed_kernel(const float* __restrict__ images,
                                                    const float* __restrict__ Wemb,
                                                    const float* __restrict__ bemb,
                                                    const float* __restrict__ cls,
                                                    const float* __restrict__ pos,
                                                    float* __restrict__ tok) {
    int b = blockIdx.x;
    int n = b / S_LEN, s = b % S_LEN;
    int t = threadIdx.x;
    __shared__ float p[16];
    if (s > 0 && t < 16) p[t] = images[n * 4096 + (s - 1) * 16 + t];
    __syncthreads();
    for (int u = 0; u < 3; ++u) {
        int d = t + 256 * u;
        float acc;
        if (s == 0) {
            acc = cls[d];
        } else {
            acc = bemb[d];
            const float4* w = (const float4*)(Wemb + d * 16);
            float4 w0 = w[0], w1 = w[1], w2 = w[2], w3 = w[3];
            acc += p[0] * w0.x + p[1] * w0.y + p[2] * w0.z + p[3] * w0.w;
            acc += p[4] * w1.x + p[5] * w1.y + p[6] * w1.z + p[7] * w1.w;
            acc += p[8] * w2.x + p[9] * w2.y + p[10] * w2.z + p[11] * w2.w;
            acc += p[12] * w3.x + p[13] * w3.y + p[14] * w3.z + p[15] * w3.w;
        }
        tok[(size_t)b * 768 + d] = acc + pos[s * 768 + d];
    }
}

// ---------------- layernorm -> bf16 ----------------
__global__ __launch_bounds__(256) void ln_kernel(const float* __restrict__ x,
                                                 const float* __restrict__ g,
                                                 const float* __restrict__ b,
                                                 ushort_t* __restrict__ y) {
    int row = blockIdx.x;
    int t = threadIdx.x;
    const float* xr = x + (size_t)row * 768;
    float v0 = xr[t], v1 = xr[t + 256], v2 = xr[t + 512];
    float s = v0 + v1 + v2;
    float sq = v0 * v0 + v1 * v1 + v2 * v2;
    for (int o = 32; o; o >>= 1) {
        s += __shfl_xor(s, o);
        sq += __shfl_xor(sq, o);
    }
    __shared__ float red[8];
    if ((t & 63) == 0) { red[(t >> 6) * 2] = s; red[(t >> 6) * 2 + 1] = sq; }
    __syncthreads();
    float ts = red[0] + red[2] + red[4] + red[6];
    float tq = red[1] + red[3] + red[5] + red[7];
    float mu = ts * (1.0f / 768.0f);
    float var = tq * (1.0f / 768.0f) - mu * mu;
    float rs = rsqrtf(var + 1e-5f);
    ushort_t* yr = y + (size_t)row * 768;
    yr[t]       = f2bf((v0 - mu) * rs * g[t] + b[t]);
    yr[t + 256] = f2bf((v1 - mu) * rs * g[t + 256] + b[t + 256]);
    yr[t + 512] = f2bf((v2 - mu) * rs * g[t + 512] + b[t + 512]);
}

// ---------------- per-layer QKV weight pack: wqkv[h][o3][d] bf16, o3 = q|k|v ----------------
__global__ __launch_bounds__(256) void conv_wqkv(const float* __restrict__ Wq,
                                                 const float* __restrict__ Wk,
                                                 const float* __restrict__ Wv,
                                                 ushort_t* __restrict__ out) {
    int idx = (blockIdx.x * 256 + threadIdx.x) * 4;
    if (idx >= H_HEADS * 192 * 64) return;
    int h = idx / (192 * 64);
    int rem = idx - h * 192 * 64;
    int o3 = rem >> 6, d = rem & 63;
    const float* src;
    int o;
    if (o3 < 64)       { src = Wq; o = o3; }
    else if (o3 < 128) { src = Wk; o = o3 - 64; }
    else               { src = Wv; o = o3 - 128; }
    float4 v = *(const float4*)(src + ((size_t)(h * 64 + o)) * 64 + d);
    out[idx + 0] = f2bf(v.x); out[idx + 1] = f2bf(v.y);
    out[idx + 2] = f2bf(v.z); out[idx + 3] = f2bf(v.w);
}

// ---------------- MFMA QKV: block = (128 token rows, head). A in swizzled LDS, W from L1 ----
__global__ __launch_bounds__(256) void qkv_mfma(const ushort_t* __restrict__ xbf,
                                                const ushort_t* __restrict__ wqkv,
                                                const float* __restrict__ bq,
                                                const float* __restrict__ bk,
                                                const float* __restrict__ bv,
                                                ushort_t* __restrict__ qhb,
                                                ushort_t* __restrict__ khb,
                                                ushort_t* __restrict__ vtb) {
    __shared__ ushort_t As[128 * 64];
    int rt = blockIdx.x;            // 0..128
    int h = blockIdx.y;
    int t = threadIdx.x, lane = t & 63, wid = t >> 6;
    int wr = wid >> 1, wc = wid & 1;     // wave tile: 64 rows x 96 cols
    {   // stage A rows rt*128.., cols h*64..+64, slot-swizzled (8 groups x 8 shorts)
        int lr = t >> 3, lg = t & 7;
#pragma unroll
        for (int u = 0; u < 4; ++u) {
            int r = u * 32 + lr;
            int grow = rt * 128 + r;
            if (grow >= R_ROWS) grow = R_ROWS - 1;
            short8 a = *(const short8*)(xbf + (size_t)grow * 768 + h * 64 + lg * 8);
            *(short8*)&As[r * 64 + (lg ^ (r & 7)) * 8] = a;
        }
    }
    __syncthreads();
    int frow = lane & 15, g = lane >> 4;
    const ushort_t* wb = wqkv + (size_t)h * (192 * 64);
    f32x4 acc[4][6];
#pragma unroll
    for (int m = 0; m < 4; ++m)
#pragma unroll
        for (int n = 0; n < 6; ++n) acc[m][n] = (f32x4){0.f, 0.f, 0.f, 0.f};
#pragma unroll
    for (int kk = 0; kk < 2; ++kk) {
        short8 af[4], bfr[6];
#pragma unroll
        for (int m = 0; m < 4; ++m) {
            int r = wr * 64 + m * 16 + frow;
            af[m] = *(const short8*)&As[r * 64 + ((kk * 4 + g) ^ (r & 7)) * 8];
        }
#pragma unroll
        for (int n = 0; n < 6; ++n)
            bfr[n] = *(const short8*)(wb + (size_t)(wc * 96 + n * 16 + frow) * 64 + kk * 32 + g * 8);
#pragma unroll
        for (int m = 0; m < 4; ++m)
#pragma unroll
            for (int n = 0; n < 6; ++n)
                acc[m][n] = __builtin_amdgcn_mfma_f32_16x16x32_bf16(af[m], bfr[n], acc[m][n], 0, 0, 0);
    }
    // epilogue: c<64 -> q (x0.125), c<128 -> k, else v transposed
    int rl_base = wr * 64 + (g * 4);
#pragma unroll
    for (int n = 0; n < 6; ++n) {
        int c = wc * 96 + n * 16 + frow;
        float bias = (c < 64) ? bq[h * 64 + c]
                   : (c < 128) ? bk[h * 64 + c - 64]
                               : bv[h * 64 + c - 128];
#pragma unroll
        for (int m = 0; m < 4; ++m) {
#pragma unroll
            for (int j = 0; j < 4; ++j) {
                int r = rt * 128 + rl_base + m * 16 + j;
                if (r < R_ROWS) {
                    unsigned nimg = (unsigned)r / 257u;
                    unsigned s = (unsigned)r - nimg * 257u;
                    float val = acc[m][n][j] + bias;
                    if (c < 64) {
                        qhb[((size_t)(nimg * H_HEADS + h) * 257 + s) * 64 + c] = f2bf(val * 0.125f);
                    } else if (c < 128) {
                        khb[((size_t)(nimg * H_HEADS + h) * 257 + s) * 64 + (c - 64)] = f2bf(val);
                    } else {
                        vtb[(size_t)(nimg * H_HEADS + h) * (64 * SKV) + (size_t)(c - 128) * SKV + s] = f2bf(val);
                    }
                }
            }
        }
    }
}

// ---------------- MFMA flash attention (single bf16 Q/K) ----------------
__global__ __launch_bounds__(256) void attn_mfma(const ushort_t* __restrict__ qh,
                                                 const ushort_t* __restrict__ kh,
                                                 const ushort_t* __restrict__ vT,
                                                 float* __restrict__ tok) {
    __shared__ ushort_t Plds[4][1024];
    int b = blockIdx.x;
    int qt = b % 5;
    int nh = b / 5;
    int h = nh % H_HEADS, n = nh / H_HEADS;
    int t = threadIdx.x, w = t >> 6, lane = t & 63;
    int lq = lane & 15, g = lane >> 4;
    const size_t hoff = ((size_t)n * H_HEADS + h) * (S_LEN * 64);
    const ushort_t* qhp = qh + hoff;
    const ushort_t* khp = kh + hoff;
    const ushort_t* vp  = vT + ((size_t)n * H_HEADS + h) * (64 * SKV);
    char* pwave = (char*)&Plds[w][0];
    const int xorm = (lq & 7) << 4;

    int qrow = qt * 64 + w * 16 + lq;
    int qcl = qrow > 256 ? 256 : qrow;
    short8 qf[2];
#pragma unroll
    for (int kk = 0; kk < 2; ++kk)
        qf[kk] = *(const short8*)(qhp + (size_t)qcl * 64 + kk * 32 + g * 8);
    float m = -INFINITY, lsum = 0.f;
    f32x4 o[4];
#pragma unroll
    for (int dt = 0; dt < 4; ++dt) o[dt] = (f32x4){0.f, 0.f, 0.f, 0.f};

    for (int kt = 0; kt < 5; ++kt) {
        f32x4 c[4];
#pragma unroll
        for (int st = 0; st < 4; ++st) {
            int key = kt * 64 + st * 16 + lq;
            int kcl = key > 256 ? 256 : key;
            const ushort_t* krh = khp + (size_t)kcl * 64 + g * 8;
            c[st] = (f32x4){0.f, 0.f, 0.f, 0.f};
#pragma unroll
            for (int kk = 0; kk < 2; ++kk) {
                short8 ah = *(const short8*)(krh + kk * 32);
                c[st] = __builtin_amdgcn_mfma_f32_16x16x32_bf16(ah, qf[kk], c[st], 0, 0, 0);
            }
        }
        float tmax = -INFINITY;
#pragma unroll
        for (int st = 0; st < 4; ++st)
#pragma unroll
            for (int j = 0; j < 4; ++j) {
                int key = kt * 64 + st * 16 + g * 4 + j;
                float sv = (key <= 256) ? c[st][j] : -INFINITY;
                c[st][j] = sv;
                tmax = fmaxf(tmax, sv);
            }
        tmax = fmaxf(tmax, __shfl_xor(tmax, 16));
        tmax = fmaxf(tmax, __shfl_xor(tmax, 32));
        float mn = fmaxf(m, tmax);
        float scale = __expf(m - mn);
        float psum = 0.f;
        unsigned pw[4][2];
#pragma unroll
        for (int st = 0; st < 4; ++st) {
            float p0 = __expf(c[st][0] - mn), p1 = __expf(c[st][1] - mn);
            float p2 = __expf(c[st][2] - mn), p3 = __expf(c[st][3] - mn);
            psum += (p0 + p1) + (p2 + p3);
            pw[st][0] = (unsigned)f2bf(p0) | ((unsigned)f2bf(p1) << 16);
            pw[st][1] = (unsigned)f2bf(p2) | ((unsigned)f2bf(p3) << 16);
        }
        psum += __shfl_xor(psum, 16);
        psum += __shfl_xor(psum, 32);
        lsum = lsum * scale + psum;
        m = mn;
#pragma unroll
        for (int st = 0; st < 4; ++st) {
            int off = (lq * 128 + st * 32 + g * 8) ^ xorm;
            *(u32x2*)(pwave + off) = (u32x2){pw[st][0], pw[st][1]};
        }
        float s0 = __shfl(scale, g * 4 + 0);
        float s1 = __shfl(scale, g * 4 + 1);
        float s2 = __shfl(scale, g * 4 + 2);
        float s3 = __shfl(scale, g * 4 + 3);
#pragma unroll
        for (int dt = 0; dt < 4; ++dt) {
            o[dt][0] *= s0; o[dt][1] *= s1; o[dt][2] *= s2; o[dt][3] *= s3;
        }
#pragma unroll
        for (int kk = 0; kk < 2; ++kk) {
            int roff = (lq * 128 + kk * 64 + g * 16) ^ xorm;
            short8 pf = *(const short8*)(pwave + roff);
#pragma unroll
            for (int dt = 0; dt < 4; ++dt) {
                const ushort_t* vf = vp + (size_t)(dt * 16 + lq) * SKV + kt * 64 + kk * 32 + g * 8;
                o[dt] = __builtin_amdgcn_mfma_f32_16x16x32_bf16(pf, *(const short8*)vf, o[dt], 0, 0, 0);
            }
        }
    }
    float inv[4];
#pragma unroll
    for (int j = 0; j < 4; ++j) inv[j] = 1.0f / __shfl(lsum, g * 4 + j);
    int qbase = qt * 64 + w * 16;
#pragma unroll
    for (int j = 0; j < 4; ++j) {
        int qr = qbase + g * 4 + j;
        if (qr < S_LEN) {
            float* trow = tok + ((size_t)n * S_LEN + qr) * 768 + h * 64 + lq;
            trow[0]  += o[0][j] * inv[j];
            trow[16] += o[1][j] * inv[j];
            trow[32] += o[2][j] * inv[j];
            trow[48] += o[3][j] * inv[j];
        }
    }
}

// ---------------- fp32 -> bf16 strided conversion ----------------
__global__ __launch_bounds__(256) void f32_to_bf16(const float* __restrict__ in,
                                                   ushort_t* __restrict__ out,
                                                   int cols, int ld, int total) {
    int idx = (blockIdx.x * 256 + threadIdx.x) * 4;
    if (idx >= total) return;
    int r = idx / cols, c = idx % cols;
    float4 v = *(const float4*)(in + (size_t)r * ld + c);
    out[idx + 0] = f2bf(v.x); out[idx + 1] = f2bf(v.y);
    out[idx + 2] = f2bf(v.z); out[idx + 3] = f2bf(v.w);
}

// ---------------- bf16 MFMA GEMM, 128x128 tile, BK=64, global_load_lds + XOR swizzle -------
__device__ __forceinline__ float gelu_exact(float x) {
    return 0.5f * x * (1.0f + erff(x * 0.70710678118654752f));
}

// MODE 0: bias + gelu -> bf16 out.  MODE 1: (+bias) + accumulate fp32 out.
template <int MODE>
__global__ __launch_bounds__(256) void mfma_gemm(const ushort_t* __restrict__ A,
                                                 const ushort_t* __restrict__ B,
                                                 const float* __restrict__ bias,
                                                 void* __restrict__ Cv,
                                                 int K, int lda, int ldb, int ldc) {
    __shared__ ushort_t As[128 * 64];
    __shared__ ushort_t Bs[128 * 64];
    int t = threadIdx.x;
    int lane = t & 63, wid = t >> 6;
    int wr = wid >> 1, wc = wid & 1;
    int bm = blockIdx.y, bn = blockIdx.x;
    const ushort_t* Ag = A + (size_t)(bm * 128) * lda;
    const ushort_t* Bg = B + (size_t)(bn * 128) * ldb;
    int srow = t >> 3;                       // 0..31
    int swz = ((t & 7) ^ (srow & 7)) * 8;    // source pre-swizzle (T21: both sides)
    int wbase = (t & 192) * 8;               // wave-uniform LDS chunk base (shorts)
    int frow = lane & 15, g = lane >> 4;
    f32x4 acc[4][4];
#pragma unroll
    for (int m = 0; m < 4; ++m)
#pragma unroll
        for (int n = 0; n < 4; ++n) acc[m][n] = (f32x4){0.f, 0.f, 0.f, 0.f};
    for (int k0 = 0; k0 < K; k0 += 64) {
        __syncthreads();
#pragma unroll
        for (int u = 0; u < 4; ++u) {
            glds16(Ag + (size_t)(u * 32 + srow) * lda + k0 + swz, &As[u * 2048 + wbase]);
            glds16(Bg + (size_t)(u * 32 + srow) * ldb + k0 + swz, &Bs[u * 2048 + wbase]);
        }
        __syncthreads();
#pragma unroll
        for (int kk = 0; kk < 2; ++kk) {
            short8 af[4], bfr[4];
#pragma unroll
            for (int m = 0; m < 4; ++m) {
                int r = wr * 64 + m * 16 + frow;
                af[m] = *(const short8*)&As[r * 64 + (((kk * 4 + g)) ^ (r & 7)) * 8];
            }
#pragma unroll
            for (int n = 0; n < 4; ++n) {
                int r = wc * 64 + n * 16 + frow;
                bfr[n] = *(const short8*)&Bs[r * 64 + (((kk * 4 + g)) ^ (r & 7)) * 8];
            }
#pragma unroll
            for (int m = 0; m < 4; ++m)
#pragma unroll
                for (int n = 0; n < 4; ++n)
                    acc[m][n] = __builtin_amdgcn_mfma_f32_16x16x32_bf16(af[m], bfr[n], acc[m][n], 0, 0, 0);
        }
    }
    int rowbase = bm * 128 + wr * 64 + (g * 4);
    int colbase = bn * 128 + wc * 64 + frow;
#pragma unroll
    for (int n = 0; n < 4; ++n) {
        int col = colbase + n * 16;
        float bv = bias ? bias[col] : 0.f;
#pragma unroll
        for (int m = 0; m < 4; ++m) {
            int row0 = rowbase + m * 16;
#pragma unroll
            for (int j = 0; j < 4; ++j) {
                float val = acc[m][n][j] + bv;
                if (MODE == 0) {
                    ((ushort_t*)Cv)[(size_t)(row0 + j) * ldc + col] = f2bf(gelu_exact(val));
                } else {
                    float* cp = (float*)Cv + (size_t)(row0 + j) * ldc + col;
                    *cp += val;
                }
            }
        }
    }
}

// ---------------- classifier head + softmax ----------------
__global__ __launch_bounds__(64) void head_kernel(const float* __restrict__ tok,
                                                  const float* __restrict__ Whead,
                                                  const float* __restrict__ bhead,
                                                  float* __restrict__ out) {
    int n = blockIdx.x;
    int t = threadIdx.x;
    __shared__ float logits[OUT_DIM];
    if (t < OUT_DIM) {
        float acc = bhead[t];
        const float* xr = tok + (size_t)n * S_LEN * 768;
        const float* w = Whead + t * 768;
        for (int d = 0; d < 768; ++d) acc += xr[d] * w[d];
        logits[t] = acc;
    }
    __syncthreads();
    if (t == 0) {
        float m = -INFINITY;
        for (int o = 0; o < OUT_DIM; ++o) m = fmaxf(m, logits[o]);
        float ssum = 0.f;
        float e[OUT_DIM];
        for (int o = 0; o < OUT_DIM; ++o) { e[o] = expf(logits[o] - m); ssum += e[o]; }
        float inv = 1.0f / ssum;
        for (int o = 0; o < OUT_DIM; ++o) out[n * OUT_DIM + o] = e[o] * inv;
    }
}

extern "C" void kernel_launch(void* const* d_in, const int* in_sizes, int n_in,
                              void* d_out, int out_size, void* d_ws, size_t ws_size,
                              hipStream_t stream) {
    const float* images = (const float*)d_in[0];
    const float* Wemb   = (const float*)d_in[1];
    const float* bemb   = (const float*)d_in[2];
    const float* cls    = (const float*)d_in[3];
    const float* Wq     = (const float*)d_in[4];
    const float* bq     = (const float*)d_in[5];
    const float* Wk     = (const float*)d_in[6];
    const float* bk     = (const float*)d_in[7];
    const float* Wv     = (const float*)d_in[8];
    const float* bv     = (const float*)d_in[9];
    const float* ln1_g  = (const float*)d_in[10];
    const float* ln1_b  = (const float*)d_in[11];
    const float* ln2_g  = (const float*)d_in[12];
    const float* ln2_b  = (const float*)d_in[13];
    const float* W1     = (const float*)d_in[14];
    const float* b1     = (const float*)d_in[15];
    const float* W2     = (const float*)d_in[16];
    const float* b2     = (const float*)d_in[17];
    const float* Whead  = (const float*)d_in[18];
    const float* bhead  = (const float*)d_in[19];
    float* out = (float*)d_out;

    const size_t TOKP = (size_t)R_PAD * D_MODEL;               // 12,681,216
    const size_t QKSZ = (size_t)N_IMG * H_HEADS * S_LEN * 64;  // 12,632,064
    const size_t VTSZ = (size_t)N_IMG * H_HEADS * 64 * SKV;    // 15,728,640
    float* ws   = (float*)d_ws;
    float* pos  = ws;                                          // 197,376 f32
    float* tok  = pos + 197376;                                // TOKP f32
    ushort_t* xbf  = (ushort_t*)(tok + TOKP);                  // TOKP bf16
    ushort_t* qhb  = xbf + TOKP;                               // QKSZ
    ushort_t* khb  = qhb + QKSZ;                               // QKSZ
    ushort_t* vtb  = khb + QKSZ;                               // VTSZ
    ushort_t* wqkvbf = vtb + VTSZ;                             // 147,456
    ushort_t* w1bf = wqkvbf + H_HEADS * 192 * 64;              // 1536*768
    ushort_t* w2bf = w1bf + (size_t)F_CHUNK * D_MODEL;         // 768*1536
    ushort_t* hid  = qhb;  // overlay: R_PAD*1536 bf16 fits in qhb+khb(+start of vtb)

    pos_kernel<<<S_LEN, 256, 0, stream>>>(pos);
    embed_kernel<<<R_ROWS, 256, 0, stream>>>(images, Wemb, bemb, cls, pos, tok);

    for (int l = 0; l < L_LAYERS; ++l) {
        const size_t wqkv_off = (size_t)l * H_HEADS * 64 * 64;
        const size_t bqkv_off = (size_t)l * H_HEADS * 64;
        ln_kernel<<<R_ROWS, 256, 0, stream>>>(tok, ln1_g + l * 768, ln1_b + l * 768, xbf);
        conv_wqkv<<<144, 256, 0, stream>>>(Wq + wqkv_off, Wk + wqkv_off, Wv + wqkv_off, wqkvbf);
        qkv_mfma<<<dim3(R_PAD / 128, H_HEADS), 256, 0, stream>>>(
            xbf, wqkvbf, bq + bqkv_off, bk + bqkv_off, bv + bqkv_off, qhb, khb, vtb);
        attn_mfma<<<N_IMG * H_HEADS * 5, 256, 0, stream>>>(qhb, khb, vtb, tok);
        ln_kernel<<<R_ROWS, 256, 0, stream>>>(tok, ln2_g + l * 768, ln2_b + l * 768, xbf);
        for (int c = 0; c < 2; ++c) {
            int c0 = c * F_CHUNK;
            f32_to_bf16<<<1152, 256, 0, stream>>>(
                W1 + (size_t)l * F_HID * D_MODEL + (size_t)c0 * D_MODEL, w1bf,
                768, 768, F_CHUNK * 768);
            f32_to_bf16<<<1152, 256, 0, stream>>>(
                W2 + (size_t)l * D_MODEL * F_HID + c0, w2bf,
                F_CHUNK, F_HID, 768 * F_CHUNK);
            mfma_gemm<0><<<dim3(F_CHUNK / 128, R_PAD / 128), 256, 0, stream>>>(
                xbf, w1bf, b1 + (size_t)l * F_HID + c0, hid, 768, 768, 768, F_CHUNK);
            mfma_gemm<1><<<dim3(D_MODEL / 128, R_PAD / 128), 256, 0, stream>>>(
                hid, w2bf, (c == 0) ? (b2 + (size_t)l * D_MODEL) : (const float*)nullptr,
                tok, F_CHUNK, F_CHUNK, F_CHUNK, D_MODEL);
        }
    }
    head_kernel<<<N_IMG, 64, 0, stream>>>(tok, Whead, bhead, out);
}

// Round 5
// 6370.080 us; speedup vs baseline: 16.6880x; 1.1852x over previous
//
#include <hip/hip_runtime.h>
#include <math.h>
#include <stdint.h>

#define N_IMG 64
#define S_LEN 257
#define D_MODEL 768
#define H_HEADS 12
#define L_LAYERS 12
#define F_HID 3072
#define F_CHUNK 1536
#define OUT_DIM 10
#define R_ROWS (N_IMG * S_LEN)   // 16448
#define R_PAD 16512              // 129 * 128
#define SKV 320                  // padded key count for vT

typedef unsigned short ushort_t;
typedef __attribute__((ext_vector_type(4))) float f32x4;
typedef __attribute__((ext_vector_type(8))) short short8;
typedef __attribute__((ext_vector_type(2))) unsigned int u32x2;

__device__ __forceinline__ ushort_t f2bf(float x) {
    unsigned u = __float_as_uint(x);
    u += 0x7fffu + ((u >> 16) & 1u);
    return (ushort_t)(u >> 16);
}
__device__ __forceinline__ unsigned pack2(float a, float b) {
    return (unsigned)f2bf(a) | ((unsigned)f2bf(b) << 16);
}

// async global->LDS, 16B per lane; dest = wave-uniform base + lane*16
__device__ __forceinline__ void glds16(const ushort_t* g, const ushort_t* l) {
    __builtin_amdgcn_global_load_lds(
        (const __attribute__((address_space(1))) unsigned int*)(uintptr_t)g,
        (__attribute__((address_space(3))) unsigned int*)(uintptr_t)l,
        16, 0, 0);
}

// ---------------- positional embedding (double precision, matches numpy f64) ----------------
__global__ __launch_bounds__(256) void pos_kernel(float* __restrict__ pos) {
    int i = blockIdx.x;
    int t = threadIdx.x;
    for (int u = 0; u < 3; ++u) {
        int j = t + 256 * u;
        double e = (double)(j & ~1) / 768.0;
        double angle = (double)i * exp(-e * 9.210340371976184);
        double v = (j & 1) ? cos(angle) : sin(angle);
        pos[i * 768 + j] = (float)v;
    }
}

// ---------------- patch embed + cls + pos ----------------
__global__ __launch_bounds__(256) void embed_kernel(const float* __restrict__ images,
                                                    const float* __restrict__ Wemb,
                                                    const float* __restrict__ bemb,
                                                    const float* __restrict__ cls,
                                                    const float* __restrict__ pos,
                                                    float* __restrict__ tok) {
    int b = blockIdx.x;
    int n = b / S_LEN, s = b % S_LEN;
    int t = threadIdx.x;
    __shared__ float p[16];
    if (s > 0 && t < 16) p[t] = images[n * 4096 + (s - 1) * 16 + t];
    __syncthreads();
    for (int u = 0; u < 3; ++u) {
        int d = t + 256 * u;
        float acc;
        if (s == 0) {
            acc = cls[d];
        } else {
            acc = bemb[d];
            const float4* w = (const float4*)(Wemb + d * 16);
            float4 w0 = w[0], w1 = w[1], w2 = w[2], w3 = w[3];
            acc += p[0] * w0.x + p[1] * w0.y + p[2] * w0.z + p[3] * w0.w;
            acc += p[4] * w1.x + p[5] * w1.y + p[6] * w1.z + p[7] * w1.w;
            acc += p[8] * w2.x + p[9] * w2.y + p[10] * w2.z + p[11] * w2.w;
            acc += p[12] * w3.x + p[13] * w3.y + p[14] * w3.z + p[15] * w3.w;
        }
        tok[(size_t)b * 768 + d] = acc + pos[s * 768 + d];
    }
}

// ---------------- layernorm -> bf16 : one wave per row ----------------
__global__ __launch_bounds__(256) void ln_kernel(const float* __restrict__ x,
                                                 const float* __restrict__ g,
                                                 const float* __restrict__ b,
                                                 ushort_t* __restrict__ y) {
    int row = blockIdx.x * 4 + (threadIdx.x >> 6);
    int lane = threadIdx.x & 63;
    const float* xr = x + (size_t)row * 768 + lane * 4;
    float4 a0 = *(const float4*)xr;
    float4 a1 = *(const float4*)(xr + 256);
    float4 a2 = *(const float4*)(xr + 512);
    float s = (a0.x + a0.y + a0.z + a0.w) + (a1.x + a1.y + a1.z + a1.w) + (a2.x + a2.y + a2.z + a2.w);
    float sq = a0.x*a0.x + a0.y*a0.y + a0.z*a0.z + a0.w*a0.w
             + a1.x*a1.x + a1.y*a1.y + a1.z*a1.z + a1.w*a1.w
             + a2.x*a2.x + a2.y*a2.y + a2.z*a2.z + a2.w*a2.w;
    for (int o = 32; o; o >>= 1) {
        s += __shfl_xor(s, o);
        sq += __shfl_xor(sq, o);
    }
    float mu = s * (1.0f / 768.0f);
    float var = sq * (1.0f / 768.0f) - mu * mu;
    float rs = rsqrtf(var + 1e-5f);
    ushort_t* yr = y + (size_t)row * 768 + lane * 4;
#pragma unroll
    for (int i = 0; i < 3; ++i) {
        float4 av = (i == 0) ? a0 : (i == 1) ? a1 : a2;
        const float4 gg = *(const float4*)(g + lane * 4 + i * 256);
        const float4 bb = *(const float4*)(b + lane * 4 + i * 256);
        float o0 = (av.x - mu) * rs * gg.x + bb.x;
        float o1 = (av.y - mu) * rs * gg.y + bb.y;
        float o2 = (av.z - mu) * rs * gg.z + bb.z;
        float o3 = (av.w - mu) * rs * gg.w + bb.w;
        *(u32x2*)(yr + i * 256) = (u32x2){pack2(o0, o1), pack2(o2, o3)};
    }
}

// ---------------- per-layer weight conversion: wqkv pack + full W1 + full W2 ----------------
__global__ __launch_bounds__(256) void conv_layer(const float* __restrict__ Wq,
                                                  const float* __restrict__ Wk,
                                                  const float* __restrict__ Wv,
                                                  const float* __restrict__ W1l,
                                                  const float* __restrict__ W2l,
                                                  ushort_t* __restrict__ wqkvbf,
                                                  ushort_t* __restrict__ w1bf,
                                                  ushort_t* __restrict__ w2bf) {
    const int NQKV = H_HEADS * 192 * 64;       // 147456
    const int NW = F_HID * D_MODEL;            // 2359296
    int idx = (blockIdx.x * 256 + threadIdx.x) * 4;
    if (idx < NQKV) {
        int h = idx / (192 * 64);
        int rem = idx - h * 192 * 64;
        int o3 = rem >> 6, d = rem & 63;
        const float* src;
        int o;
        if (o3 < 64)       { src = Wq; o = o3; }
        else if (o3 < 128) { src = Wk; o = o3 - 64; }
        else               { src = Wv; o = o3 - 128; }
        float4 v = *(const float4*)(src + ((size_t)(h * 64 + o)) * 64 + d);
        *(u32x2*)(wqkvbf + idx) = (u32x2){pack2(v.x, v.y), pack2(v.z, v.w)};
    } else if (idx < NQKV + NW) {
        int i = idx - NQKV;
        float4 v = *(const float4*)(W1l + i);
        *(u32x2*)(w1bf + i) = (u32x2){pack2(v.x, v.y), pack2(v.z, v.w)};
    } else {
        int i = idx - NQKV - NW;
        float4 v = *(const float4*)(W2l + i);
        *(u32x2*)(w2bf + i) = (u32x2){pack2(v.x, v.y), pack2(v.z, v.w)};
    }
}

// ---------------- MFMA QKV: block = (128 token rows, head); swapped-operand epilogue -------
__global__ __launch_bounds__(256) void qkv_mfma(const ushort_t* __restrict__ xbf,
                                                const ushort_t* __restrict__ wqkv,
                                                const float* __restrict__ bq,
                                                const float* __restrict__ bk,
                                                const float* __restrict__ bv,
                                                ushort_t* __restrict__ qhb,
                                                ushort_t* __restrict__ khb,
                                                ushort_t* __restrict__ vtb) {
    __shared__ ushort_t As[128 * 64];
    int rt = blockIdx.x;            // 0..128
    int h = blockIdx.y;
    int t = threadIdx.x, lane = t & 63, wid = t >> 6;
    int wr = wid >> 1, wc = wid & 1;     // wave tile: 64 rows x 96 cols
    {
        int lr = t >> 3, lg = t & 7;
#pragma unroll
        for (int u = 0; u < 4; ++u) {
            int r = u * 32 + lr;
            int grow = rt * 128 + r;
            if (grow >= R_ROWS) grow = R_ROWS - 1;
            short8 a = *(const short8*)(xbf + (size_t)grow * 768 + h * 64 + lg * 8);
            *(short8*)&As[r * 64 + (lg ^ (r & 7)) * 8] = a;
        }
    }
    __syncthreads();
    int frow = lane & 15, g = lane >> 4;
    const ushort_t* wb = wqkv + (size_t)h * (192 * 64);
    f32x4 acc[4][6];
#pragma unroll
    for (int m = 0; m < 4; ++m)
#pragma unroll
        for (int n = 0; n < 6; ++n) acc[m][n] = (f32x4){0.f, 0.f, 0.f, 0.f};
#pragma unroll
    for (int kk = 0; kk < 2; ++kk) {
        short8 af[4], bfr[6];
#pragma unroll
        for (int m = 0; m < 4; ++m) {
            int r = wr * 64 + m * 16 + frow;
            af[m] = *(const short8*)&As[r * 64 + ((kk * 4 + g) ^ (r & 7)) * 8];
        }
#pragma unroll
        for (int n = 0; n < 6; ++n)
            bfr[n] = *(const short8*)(wb + (size_t)(wc * 96 + n * 16 + frow) * 64 + kk * 32 + g * 8);
        // swapped: C[row=token(frow)][col=output(g*4+j)]
#pragma unroll
        for (int m = 0; m < 4; ++m)
#pragma unroll
            for (int n = 0; n < 6; ++n)
                acc[m][n] = __builtin_amdgcn_mfma_f32_16x16x32_bf16(bfr[n], af[m], acc[m][n], 0, 0, 0);
    }
#pragma unroll
    for (int m = 0; m < 4; ++m) {
        int token = rt * 128 + wr * 64 + m * 16 + frow;
        if (token < R_ROWS) {
            unsigned nimg = (unsigned)token / 257u;
            unsigned s = (unsigned)token - nimg * 257u;
            size_t qk_base = ((size_t)(nimg * H_HEADS + h) * 257 + s) * 64;
            size_t v_base = (size_t)(nimg * H_HEADS + h) * (64 * SKV);
#pragma unroll
            for (int n = 0; n < 6; ++n) {
                int c = wc * 96 + n * 16 + g * 4;
                f32x4 a = acc[m][n];
                if (c < 64) {
                    const float4 bb = *(const float4*)(bq + h * 64 + c);
                    *(u32x2*)(qhb + qk_base + c) = (u32x2){
                        pack2((a[0] + bb.x) * 0.125f, (a[1] + bb.y) * 0.125f),
                        pack2((a[2] + bb.z) * 0.125f, (a[3] + bb.w) * 0.125f)};
                } else if (c < 128) {
                    const float4 bb = *(const float4*)(bk + h * 64 + (c - 64));
                    *(u32x2*)(khb + qk_base + (c - 64)) = (u32x2){
                        pack2(a[0] + bb.x, a[1] + bb.y), pack2(a[2] + bb.z, a[3] + bb.w)};
                } else {
                    const float4 bb = *(const float4*)(bv + h * 64 + (c - 128));
                    vtb[v_base + (size_t)(c - 128 + 0) * SKV + s] = f2bf(a[0] + bb.x);
                    vtb[v_base + (size_t)(c - 128 + 1) * SKV + s] = f2bf(a[1] + bb.y);
                    vtb[v_base + (size_t)(c - 128 + 2) * SKV + s] = f2bf(a[2] + bb.z);
                    vtb[v_base + (size_t)(c - 128 + 3) * SKV + s] = f2bf(a[3] + bb.w);
                }
            }
        }
    }
}

// ---------------- MFMA flash attention (swapped PV: stats lane == output lane) --------------
__global__ __launch_bounds__(256) void attn_mfma(const ushort_t* __restrict__ qh,
                                                 const ushort_t* __restrict__ kh,
                                                 const ushort_t* __restrict__ vT,
                                                 float* __restrict__ tok) {
    __shared__ ushort_t Plds[4][1024];
    int b = blockIdx.x;
    int qt = b % 5;
    int nh = b / 5;
    int h = nh % H_HEADS, n = nh / H_HEADS;
    int t = threadIdx.x, w = t >> 6, lane = t & 63;
    int lq = lane & 15, g = lane >> 4;
    const size_t hoff = ((size_t)n * H_HEADS + h) * (S_LEN * 64);
    const ushort_t* qhp = qh + hoff;
    const ushort_t* khp = kh + hoff;
    const ushort_t* vp  = vT + ((size_t)n * H_HEADS + h) * (64 * SKV);
    char* pwave = (char*)&Plds[w][0];
    const int xorm = (lq & 7) << 4;

    int qrow = qt * 64 + w * 16 + lq;
    int qcl = qrow > 256 ? 256 : qrow;
    short8 qf[2];
#pragma unroll
    for (int kk = 0; kk < 2; ++kk)
        qf[kk] = *(const short8*)(qhp + (size_t)qcl * 64 + kk * 32 + g * 8);
    float m = -INFINITY, lsum = 0.f;
    f32x4 o[4];
#pragma unroll
    for (int dt = 0; dt < 4; ++dt) o[dt] = (f32x4){0.f, 0.f, 0.f, 0.f};

    for (int kt = 0; kt < 5; ++kt) {
        f32x4 c[4];
#pragma unroll
        for (int st = 0; st < 4; ++st) {
            int key = kt * 64 + st * 16 + lq;
            int kcl = key > 256 ? 256 : key;
            const ushort_t* krh = khp + (size_t)kcl * 64 + g * 8;
            c[st] = (f32x4){0.f, 0.f, 0.f, 0.f};
#pragma unroll
            for (int kk = 0; kk < 2; ++kk) {
                short8 ah = *(const short8*)(krh + kk * 32);
                c[st] = __builtin_amdgcn_mfma_f32_16x16x32_bf16(ah, qf[kk], c[st], 0, 0, 0);
            }
        }
        float tmax = -INFINITY;
#pragma unroll
        for (int st = 0; st < 4; ++st)
#pragma unroll
            for (int j = 0; j < 4; ++j) {
                int key = kt * 64 + st * 16 + g * 4 + j;
                float sv = (key <= 256) ? c[st][j] : -INFINITY;
                c[st][j] = sv;
                tmax = fmaxf(tmax, sv);
            }
        tmax = fmaxf(tmax, __shfl_xor(tmax, 16));
        tmax = fmaxf(tmax, __shfl_xor(tmax, 32));
        float mn = fmaxf(m, tmax);
        float scale = __expf(m - mn);
        float psum = 0.f;
        unsigned pw[4][2];
#pragma unroll
        for (int st = 0; st < 4; ++st) {
            float p0 = __expf(c[st][0] - mn), p1 = __expf(c[st][1] - mn);
            float p2 = __expf(c[st][2] - mn), p3 = __expf(c[st][3] - mn);
            psum += (p0 + p1) + (p2 + p3);
            pw[st][0] = pack2(p0, p1);
            pw[st][1] = pack2(p2, p3);
        }
        psum += __shfl_xor(psum, 16);
        psum += __shfl_xor(psum, 32);
        lsum = lsum * scale + psum;
        m = mn;
#pragma unroll
        for (int st = 0; st < 4; ++st) {
            int off = (lq * 128 + st * 32 + g * 8) ^ xorm;
            *(u32x2*)(pwave + off) = (u32x2){pw[st][0], pw[st][1]};
        }
        // rescale O with the lane's own scale (stats live at q=lq = output col)
#pragma unroll
        for (int dt = 0; dt < 4; ++dt) {
            o[dt][0] *= scale; o[dt][1] *= scale; o[dt][2] *= scale; o[dt][3] *= scale;
        }
        // PV swapped: mfma(V^T, P) -> C[row=d][col=q=lq]
#pragma unroll
        for (int kk = 0; kk < 2; ++kk) {
            int roff = (lq * 128 + kk * 64 + g * 16) ^ xorm;
            short8 pf = *(const short8*)(pwave + roff);
#pragma unroll
            for (int dt = 0; dt < 4; ++dt) {
                const ushort_t* vf = vp + (size_t)(dt * 16 + lq) * SKV + kt * 64 + kk * 32 + g * 8;
                o[dt] = __builtin_amdgcn_mfma_f32_16x16x32_bf16(*(const short8*)vf, pf, o[dt], 0, 0, 0);
            }
        }
    }
    float inv = 1.0f / lsum;
    int qr = qt * 64 + w * 16 + lq;
    if (qr < S_LEN) {
        float* trow = tok + ((size_t)n * S_LEN + qr) * 768 + h * 64 + g * 4;
#pragma unroll
        for (int dt = 0; dt < 4; ++dt) {
            float4 old = *(const float4*)(trow + dt * 16);
            old.x += o[dt][0] * inv;
            old.y += o[dt][1] * inv;
            old.z += o[dt][2] * inv;
            old.w += o[dt][3] * inv;
            *(float4*)(trow + dt * 16) = old;
        }
    }
}

// ---------------- fast exact-erf GELU (A&S 7.1.26, abs err 1.5e-7) ----------------
__device__ __forceinline__ float gelu_fast(float x) {
    float s = fabsf(x) * 0.70710678118654752f;
    float t = 1.0f / (1.0f + 0.3275911f * s);
    float y = t * (0.254829592f + t * (-0.284496736f + t * (1.421413741f +
              t * (-1.453152027f + t * 1.061405429f))));
    float erfa = 1.0f - y * __expf(-s * s);
    float erfv = copysignf(erfa, x);
    return 0.5f * x * (1.0f + erfv);
}

// ---------------- bf16 MFMA GEMM, 128x128, BK=64, glds + swizzle, swapped epilogue ---------
// MODE 0: bias + gelu -> bf16 out.  MODE 1: (+bias) + accumulate fp32 out.
template <int MODE>
__global__ __launch_bounds__(256) void mfma_gemm(const ushort_t* __restrict__ A,
                                                 const ushort_t* __restrict__ B,
                                                 const float* __restrict__ bias,
                                                 void* __restrict__ Cv,
                                                 int K, int lda, int ldb, int ldc) {
    __shared__ ushort_t As[128 * 64];
    __shared__ ushort_t Bs[128 * 64];
    int t = threadIdx.x;
    int lane = t & 63, wid = t >> 6;
    int wr = wid >> 1, wc = wid & 1;
    int bm = blockIdx.y, bn = blockIdx.x;
    const ushort_t* Ag = A + (size_t)(bm * 128) * lda;
    const ushort_t* Bg = B + (size_t)(bn * 128) * ldb;
    int srow = t >> 3;                       // 0..31
    int swz = ((t & 7) ^ (srow & 7)) * 8;    // source pre-swizzle
    int wbase = (t & 192) * 8;               // wave-uniform LDS chunk base (shorts)
    int frow = lane & 15, g = lane >> 4;
    f32x4 acc[4][4];
#pragma unroll
    for (int m = 0; m < 4; ++m)
#pragma unroll
        for (int n = 0; n < 4; ++n) acc[m][n] = (f32x4){0.f, 0.f, 0.f, 0.f};
    for (int k0 = 0; k0 < K; k0 += 64) {
        __syncthreads();
#pragma unroll
        for (int u = 0; u < 4; ++u) {
            glds16(Ag + (size_t)(u * 32 + srow) * lda + k0 + swz, &As[u * 2048 + wbase]);
            glds16(Bg + (size_t)(u * 32 + srow) * ldb + k0 + swz, &Bs[u * 2048 + wbase]);
        }
        __syncthreads();
#pragma unroll
        for (int kk = 0; kk < 2; ++kk) {
            short8 af[4], bfr[4];
#pragma unroll
            for (int m = 0; m < 4; ++m) {
                int r = wr * 64 + m * 16 + frow;
                af[m] = *(const short8*)&As[r * 64 + (((kk * 4 + g)) ^ (r & 7)) * 8];
            }
#pragma unroll
            for (int n = 0; n < 4; ++n) {
                int r = wc * 64 + n * 16 + frow;
                bfr[n] = *(const short8*)&Bs[r * 64 + (((kk * 4 + g)) ^ (r & 7)) * 8];
            }
            // swapped: C[row=A-row(frow)][col=B-row(g*4+j)]
#pragma unroll
            for (int m = 0; m < 4; ++m)
#pragma unroll
                for (int n = 0; n < 4; ++n)
                    acc[m][n] = __builtin_amdgcn_mfma_f32_16x16x32_bf16(bfr[n], af[m], acc[m][n], 0, 0, 0);
        }
    }
    int row0 = bm * 128 + wr * 64 + frow;
    int col0 = bn * 128 + wc * 64 + g * 4;
#pragma unroll
    for (int n = 0; n < 4; ++n) {
        int col = col0 + n * 16;
        float4 bb = {0.f, 0.f, 0.f, 0.f};
        if (bias) bb = *(const float4*)(bias + col);
#pragma unroll
        for (int m = 0; m < 4; ++m) {
            int row = row0 + m * 16;
            f32x4 a = acc[m][n];
            float v0 = a[0] + bb.x, v1 = a[1] + bb.y, v2 = a[2] + bb.z, v3 = a[3] + bb.w;
            if (MODE == 0) {
                v0 = gelu_fast(v0); v1 = gelu_fast(v1); v2 = gelu_fast(v2); v3 = gelu_fast(v3);
                *(u32x2*)((ushort_t*)Cv + (size_t)row * ldc + col) =
                    (u32x2){pack2(v0, v1), pack2(v2, v3)};
            } else {
                float* cp = (float*)Cv + (size_t)row * ldc + col;
                float4 old = *(const float4*)cp;
                old.x += v0; old.y += v1; old.z += v2; old.w += v3;
                *(float4*)cp = old;
            }
        }
    }
}

// ---------------- classifier head + softmax ----------------
__global__ __launch_bounds__(64) void head_kernel(const float* __restrict__ tok,
                                                  const float* __restrict__ Whead,
                                                  const float* __restrict__ bhead,
                                                  float* __restrict__ out) {
    int n = blockIdx.x;
    int t = threadIdx.x;
    __shared__ float logits[OUT_DIM];
    if (t < OUT_DIM) {
        float acc = bhead[t];
        const float* xr = tok + (size_t)n * S_LEN * 768;
        const float* w = Whead + t * 768;
        for (int d = 0; d < 768; ++d) acc += xr[d] * w[d];
        logits[t] = acc;
    }
    __syncthreads();
    if (t == 0) {
        float m = -INFINITY;
        for (int o = 0; o < OUT_DIM; ++o) m = fmaxf(m, logits[o]);
        float ssum = 0.f;
        float e[OUT_DIM];
        for (int o = 0; o < OUT_DIM; ++o) { e[o] = expf(logits[o] - m); ssum += e[o]; }
        float inv = 1.0f / ssum;
        for (int o = 0; o < OUT_DIM; ++o) out[n * OUT_DIM + o] = e[o] * inv;
    }
}

extern "C" void kernel_launch(void* const* d_in, const int* in_sizes, int n_in,
                              void* d_out, int out_size, void* d_ws, size_t ws_size,
                              hipStream_t stream) {
    const float* images = (const float*)d_in[0];
    const float* Wemb   = (const float*)d_in[1];
    const float* bemb   = (const float*)d_in[2];
    const float* cls    = (const float*)d_in[3];
    const float* Wq     = (const float*)d_in[4];
    const float* bq     = (const float*)d_in[5];
    const float* Wk     = (const float*)d_in[6];
    const float* bk     = (const float*)d_in[7];
    const float* Wv     = (const float*)d_in[8];
    const float* bv     = (const float*)d_in[9];
    const float* ln1_g  = (const float*)d_in[10];
    const float* ln1_b  = (const float*)d_in[11];
    const float* ln2_g  = (const float*)d_in[12];
    const float* ln2_b  = (const float*)d_in[13];
    const float* W1     = (const float*)d_in[14];
    const float* b1     = (const float*)d_in[15];
    const float* W2     = (const float*)d_in[16];
    const float* b2     = (const float*)d_in[17];
    const float* Whead  = (const float*)d_in[18];
    const float* bhead  = (const float*)d_in[19];
    float* out = (float*)d_out;

    const size_t TOKP = (size_t)R_PAD * D_MODEL;               // 12,681,216
    const size_t QKSZ = (size_t)N_IMG * H_HEADS * S_LEN * 64;  // 12,632,064
    const size_t VTSZ = (size_t)N_IMG * H_HEADS * 64 * SKV;    // 15,728,640
    float* ws   = (float*)d_ws;
    float* pos  = ws;                                          // 197,376 f32
    float* tok  = pos + 197376;                                // TOKP f32
    ushort_t* xbf  = (ushort_t*)(tok + TOKP);                  // TOKP bf16
    ushort_t* qhb  = xbf + TOKP;                               // QKSZ
    ushort_t* khb  = qhb + QKSZ;                               // QKSZ
    ushort_t* vtb  = khb + QKSZ;                               // VTSZ
    ushort_t* wqkvbf = vtb + VTSZ;                             // 147,456
    ushort_t* w1bf = wqkvbf + H_HEADS * 192 * 64;              // 3072*768 (full layer)
    ushort_t* w2bf = w1bf + (size_t)F_HID * D_MODEL;           // 768*3072 (full layer)
    ushort_t* hid  = qhb;  // overlay: R_PAD*1536 bf16 fits in qhb+khb(+start of vtb)

    pos_kernel<<<S_LEN, 256, 0, stream>>>(pos);
    embed_kernel<<<R_ROWS, 256, 0, stream>>>(images, Wemb, bemb, cls, pos, tok);

    for (int l = 0; l < L_LAYERS; ++l) {
        const size_t wqkv_off = (size_t)l * H_HEADS * 64 * 64;
        const size_t bqkv_off = (size_t)l * H_HEADS * 64;
        ln_kernel<<<R_ROWS / 4, 256, 0, stream>>>(tok, ln1_g + l * 768, ln1_b + l * 768, xbf);
        conv_layer<<<4752, 256, 0, stream>>>(
            Wq + wqkv_off, Wk + wqkv_off, Wv + wqkv_off,
            W1 + (size_t)l * F_HID * D_MODEL, W2 + (size_t)l * D_MODEL * F_HID,
            wqkvbf, w1bf, w2bf);
        qkv_mfma<<<dim3(R_PAD / 128, H_HEADS), 256, 0, stream>>>(
            xbf, wqkvbf, bq + bqkv_off, bk + bqkv_off, bv + bqkv_off, qhb, khb, vtb);
        attn_mfma<<<N_IMG * H_HEADS * 5, 256, 0, stream>>>(qhb, khb, vtb, tok);
        ln_kernel<<<R_ROWS / 4, 256, 0, stream>>>(tok, ln2_g + l * 768, ln2_b + l * 768, xbf);
        for (int c = 0; c < 2; ++c) {
            int c0 = c * F_CHUNK;
            mfma_gemm<0><<<dim3(F_CHUNK / 128, R_PAD / 128), 256, 0, stream>>>(
                xbf, w1bf + (size_t)c0 * D_MODEL, b1 + (size_t)l * F_HID + c0, hid,
                768, 768, 768, F_CHUNK);
            mfma_gemm<1><<<dim3(D_MODEL / 128, R_PAD / 128), 256, 0, stream>>>(
                hid, w2bf + c0, (c == 0) ? (b2 + (size_t)l * D_MODEL) : (const float*)nullptr,
                tok, F_CHUNK, F_CHUNK, F_HID, D_MODEL);
        }
    }
    head_kernel<<<N_IMG, 64, 0, stream>>>(tok, Whead, bhead, out);
}

// Round 6
// 4998.586 us; speedup vs baseline: 21.2668x; 1.2744x over previous
//
#include <hip/hip_runtime.h>
#include <math.h>
#include <stdint.h>

#define N_IMG 64
#define S_LEN 257
#define D_MODEL 768
#define H_HEADS 12
#define L_LAYERS 12
#define F_HID 3072
#define OUT_DIM 10
#define R_ROWS (N_IMG * S_LEN)   // 16448
#define R_PAD 16512              // 129 * 128
#define SKV 320                  // padded key count for vT

typedef unsigned short ushort_t;
typedef __attribute__((ext_vector_type(4))) float f32x4;
typedef __attribute__((ext_vector_type(8))) short short8;
typedef __attribute__((ext_vector_type(2))) unsigned int u32x2;

__device__ __forceinline__ ushort_t f2bf(float x) {
    unsigned u = __float_as_uint(x);
    u += 0x7fffu + ((u >> 16) & 1u);
    return (ushort_t)(u >> 16);
}
__device__ __forceinline__ unsigned pack2(float a, float b) {
    return (unsigned)f2bf(a) | ((unsigned)f2bf(b) << 16);
}

// async global->LDS, 16B per lane; dest = wave-uniform base + lane*16
__device__ __forceinline__ void glds16(const ushort_t* g, const ushort_t* l) {
    __builtin_amdgcn_global_load_lds(
        (const __attribute__((address_space(1))) unsigned int*)(uintptr_t)g,
        (__attribute__((address_space(3))) unsigned int*)(uintptr_t)l,
        16, 0, 0);
}

// ---------------- positional embedding (double precision, matches numpy f64) ----------------
__global__ __launch_bounds__(256) void pos_kernel(float* __restrict__ pos) {
    int i = blockIdx.x;
    int t = threadIdx.x;
    for (int u = 0; u < 3; ++u) {
        int j = t + 256 * u;
        double e = (double)(j & ~1) / 768.0;
        double angle = (double)i * exp(-e * 9.210340371976184);
        double v = (j & 1) ? cos(angle) : sin(angle);
        pos[i * 768 + j] = (float)v;
    }
}

// ---------------- patch embed + cls + pos ----------------
__global__ __launch_bounds__(256) void embed_kernel(const float* __restrict__ images,
                                                    const float* __restrict__ Wemb,
                                                    const float* __restrict__ bemb,
                                                    const float* __restrict__ cls,
                                                    const float* __restrict__ pos,
                                                    float* __restrict__ tok) {
    int b = blockIdx.x;
    int n = b / S_LEN, s = b % S_LEN;
    int t = threadIdx.x;
    __shared__ float p[16];
    if (s > 0 && t < 16) p[t] = images[n * 4096 + (s - 1) * 16 + t];
    __syncthreads();
    for (int u = 0; u < 3; ++u) {
        int d = t + 256 * u;
        float acc;
        if (s == 0) {
            acc = cls[d];
        } else {
            acc = bemb[d];
            const float4* w = (const float4*)(Wemb + d * 16);
            float4 w0 = w[0], w1 = w[1], w2 = w[2], w3 = w[3];
            acc += p[0] * w0.x + p[1] * w0.y + p[2] * w0.z + p[3] * w0.w;
            acc += p[4] * w1.x + p[5] * w1.y + p[6] * w1.z + p[7] * w1.w;
            acc += p[8] * w2.x + p[9] * w2.y + p[10] * w2.z + p[11] * w2.w;
            acc += p[12] * w3.x + p[13] * w3.y + p[14] * w3.z + p[15] * w3.w;
        }
        tok[(size_t)b * 768 + d] = acc + pos[s * 768 + d];
    }
}

// ---------------- layernorm -> bf16 : one wave per row ----------------
__global__ __launch_bounds__(256) void ln_kernel(const float* __restrict__ x,
                                                 const float* __restrict__ g,
                                                 const float* __restrict__ b,
                                                 ushort_t* __restrict__ y) {
    int row = blockIdx.x * 4 + (threadIdx.x >> 6);
    int lane = threadIdx.x & 63;
    const float* xr = x + (size_t)row * 768 + lane * 4;
    float4 a0 = *(const float4*)xr;
    float4 a1 = *(const float4*)(xr + 256);
    float4 a2 = *(const float4*)(xr + 512);
    float s = (a0.x + a0.y + a0.z + a0.w) + (a1.x + a1.y + a1.z + a1.w) + (a2.x + a2.y + a2.z + a2.w);
    float sq = a0.x*a0.x + a0.y*a0.y + a0.z*a0.z + a0.w*a0.w
             + a1.x*a1.x + a1.y*a1.y + a1.z*a1.z + a1.w*a1.w
             + a2.x*a2.x + a2.y*a2.y + a2.z*a2.z + a2.w*a2.w;
    for (int o = 32; o; o >>= 1) {
        s += __shfl_xor(s, o);
        sq += __shfl_xor(sq, o);
    }
    float mu = s * (1.0f / 768.0f);
    float var = sq * (1.0f / 768.0f) - mu * mu;
    float rs = rsqrtf(var + 1e-5f);
    ushort_t* yr = y + (size_t)row * 768 + lane * 4;
#pragma unroll
    for (int i = 0; i < 3; ++i) {
        float4 av = (i == 0) ? a0 : (i == 1) ? a1 : a2;
        const float4 gg = *(const float4*)(g + lane * 4 + i * 256);
        const float4 bb = *(const float4*)(b + lane * 4 + i * 256);
        float o0 = (av.x - mu) * rs * gg.x + bb.x;
        float o1 = (av.y - mu) * rs * gg.y + bb.y;
        float o2 = (av.z - mu) * rs * gg.z + bb.z;
        float o3 = (av.w - mu) * rs * gg.w + bb.w;
        *(u32x2*)(yr + i * 256) = (u32x2){pack2(o0, o1), pack2(o2, o3)};
    }
}

// ---------------- per-layer weight conversion: wqkv pack + full W1 + full W2 ----------------
__global__ __launch_bounds__(256) void conv_layer(const float* __restrict__ Wq,
                                                  const float* __restrict__ Wk,
                                                  const float* __restrict__ Wv,
                                                  const float* __restrict__ W1l,
                                                  const float* __restrict__ W2l,
                                                  ushort_t* __restrict__ wqkvbf,
                                                  ushort_t* __restrict__ w1bf,
                                                  ushort_t* __restrict__ w2bf) {
    const int NQKV = H_HEADS * 192 * 64;       // 147456
    const int NW = F_HID * D_MODEL;            // 2359296
    int idx = (blockIdx.x * 256 + threadIdx.x) * 4;
    if (idx < NQKV) {
        int h = idx / (192 * 64);
        int rem = idx - h * 192 * 64;
        int o3 = rem >> 6, d = rem & 63;
        const float* src;
        int o;
        if (o3 < 64)       { src = Wq; o = o3; }
        else if (o3 < 128) { src = Wk; o = o3 - 64; }
        else               { src = Wv; o = o3 - 128; }
        float4 v = *(const float4*)(src + ((size_t)(h * 64 + o)) * 64 + d);
        *(u32x2*)(wqkvbf + idx) = (u32x2){pack2(v.x, v.y), pack2(v.z, v.w)};
    } else if (idx < NQKV + NW) {
        int i = idx - NQKV;
        float4 v = *(const float4*)(W1l + i);
        *(u32x2*)(w1bf + i) = (u32x2){pack2(v.x, v.y), pack2(v.z, v.w)};
    } else {
        int i = idx - NQKV - NW;
        float4 v = *(const float4*)(W2l + i);
        *(u32x2*)(w2bf + i) = (u32x2){pack2(v.x, v.y), pack2(v.z, v.w)};
    }
}

// ---------------- MFMA QKV: block = (128 token rows, head); swapped-operand epilogue -------
__global__ __launch_bounds__(256) void qkv_mfma(const ushort_t* __restrict__ xbf,
                                                const ushort_t* __restrict__ wqkv,
                                                const float* __restrict__ bq,
                                                const float* __restrict__ bk,
                                                const float* __restrict__ bv,
                                                ushort_t* __restrict__ qhb,
                                                ushort_t* __restrict__ khb,
                                                ushort_t* __restrict__ vtb) {
    __shared__ ushort_t As[128 * 64];
    int rt = blockIdx.x;            // 0..128
    int h = blockIdx.y;
    int t = threadIdx.x, lane = t & 63, wid = t >> 6;
    int wr = wid >> 1, wc = wid & 1;     // wave tile: 64 rows x 96 cols
    {
        int lr = t >> 3, lg = t & 7;
#pragma unroll
        for (int u = 0; u < 4; ++u) {
            int r = u * 32 + lr;
            int grow = rt * 128 + r;
            if (grow >= R_ROWS) grow = R_ROWS - 1;
            short8 a = *(const short8*)(xbf + (size_t)grow * 768 + h * 64 + lg * 8);
            *(short8*)&As[r * 64 + (lg ^ (r & 7)) * 8] = a;
        }
    }
    __syncthreads();
    int frow = lane & 15, g = lane >> 4;
    const ushort_t* wb = wqkv + (size_t)h * (192 * 64);
    f32x4 acc[4][6];
#pragma unroll
    for (int m = 0; m < 4; ++m)
#pragma unroll
        for (int n = 0; n < 6; ++n) acc[m][n] = (f32x4){0.f, 0.f, 0.f, 0.f};
#pragma unroll
    for (int kk = 0; kk < 2; ++kk) {
        short8 af[4], bfr[6];
#pragma unroll
        for (int m = 0; m < 4; ++m) {
            int r = wr * 64 + m * 16 + frow;
            af[m] = *(const short8*)&As[r * 64 + ((kk * 4 + g) ^ (r & 7)) * 8];
        }
#pragma unroll
        for (int n = 0; n < 6; ++n)
            bfr[n] = *(const short8*)(wb + (size_t)(wc * 96 + n * 16 + frow) * 64 + kk * 32 + g * 8);
        // swapped: C[row=token(frow)][col=output(g*4+j)]
#pragma unroll
        for (int m = 0; m < 4; ++m)
#pragma unroll
            for (int n = 0; n < 6; ++n)
                acc[m][n] = __builtin_amdgcn_mfma_f32_16x16x32_bf16(bfr[n], af[m], acc[m][n], 0, 0, 0);
    }
#pragma unroll
    for (int m = 0; m < 4; ++m) {
        int token = rt * 128 + wr * 64 + m * 16 + frow;
        if (token < R_ROWS) {
            unsigned nimg = (unsigned)token / 257u;
            unsigned s = (unsigned)token - nimg * 257u;
            size_t qk_base = ((size_t)(nimg * H_HEADS + h) * 257 + s) * 64;
            size_t v_base = (size_t)(nimg * H_HEADS + h) * (64 * SKV);
#pragma unroll
            for (int n = 0; n < 6; ++n) {
                int c = wc * 96 + n * 16 + g * 4;
                f32x4 a = acc[m][n];
                if (c < 64) {
                    const float4 bb = *(const float4*)(bq + h * 64 + c);
                    *(u32x2*)(qhb + qk_base + c) = (u32x2){
                        pack2((a[0] + bb.x) * 0.125f, (a[1] + bb.y) * 0.125f),
                        pack2((a[2] + bb.z) * 0.125f, (a[3] + bb.w) * 0.125f)};
                } else if (c < 128) {
                    const float4 bb = *(const float4*)(bk + h * 64 + (c - 64));
                    *(u32x2*)(khb + qk_base + (c - 64)) = (u32x2){
                        pack2(a[0] + bb.x, a[1] + bb.y), pack2(a[2] + bb.z, a[3] + bb.w)};
                } else {
                    const float4 bb = *(const float4*)(bv + h * 64 + (c - 128));
                    vtb[v_base + (size_t)(c - 128 + 0) * SKV + s] = f2bf(a[0] + bb.x);
                    vtb[v_base + (size_t)(c - 128 + 1) * SKV + s] = f2bf(a[1] + bb.y);
                    vtb[v_base + (size_t)(c - 128 + 2) * SKV + s] = f2bf(a[2] + bb.z);
                    vtb[v_base + (size_t)(c - 128 + 3) * SKV + s] = f2bf(a[3] + bb.w);
                }
            }
        }
    }
}

// ---------------- MFMA flash attention: NST q-states per wave share K/V fragment loads ------
// NST=2: bid = qt*768 + nh (qt in {0,1}), rows qt*128 + s*64 + w*16. NST=1: rows 256.. tail.
template <int NST>
__global__ __launch_bounds__(256) void attn_mfma(const ushort_t* __restrict__ qh,
                                                 const ushort_t* __restrict__ kh,
                                                 const ushort_t* __restrict__ vT,
                                                 float* __restrict__ tok) {
    __shared__ ushort_t Plds[4][NST][1024];
    int b = blockIdx.x;
    int nh, base;
    if (NST == 2) { nh = b % 768; base = (b / 768) * 128; }
    else          { nh = b;       base = 256; }
    int h = nh % H_HEADS, n = nh / H_HEADS;
    int t = threadIdx.x, w = t >> 6, lane = t & 63;
    int lq = lane & 15, g = lane >> 4;
    const size_t hoff = ((size_t)n * H_HEADS + h) * (S_LEN * 64);
    const ushort_t* qhp = qh + hoff;
    const ushort_t* khp = kh + hoff;
    const ushort_t* vp  = vT + ((size_t)n * H_HEADS + h) * (64 * SKV);
    const int xorm = (lq & 7) << 4;

    short8 qf[NST][2];
    int qr0[NST];
    float m[NST], lsum[NST];
    f32x4 o[NST][4];
#pragma unroll
    for (int s = 0; s < NST; ++s) {
        int qrow = base + s * 64 + w * 16 + lq;
        qr0[s] = qrow;
        int qcl = qrow > 256 ? 256 : qrow;
#pragma unroll
        for (int kk = 0; kk < 2; ++kk)
            qf[s][kk] = *(const short8*)(qhp + (size_t)qcl * 64 + kk * 32 + g * 8);
        m[s] = -INFINITY; lsum[s] = 0.f;
#pragma unroll
        for (int dt = 0; dt < 4; ++dt) o[s][dt] = (f32x4){0.f, 0.f, 0.f, 0.f};
    }

    for (int kt = 0; kt < 5; ++kt) {
        // ---- K fragments (shared across states) ----
        short8 ah[4][2];
#pragma unroll
        for (int st = 0; st < 4; ++st) {
            int key = kt * 64 + st * 16 + lq;
            int kcl = key > 256 ? 256 : key;
            const ushort_t* krh = khp + (size_t)kcl * 64 + g * 8;
            ah[st][0] = *(const short8*)krh;
            ah[st][1] = *(const short8*)(krh + 32);
        }
        // ---- QK^T for all states ----
        f32x4 c[NST][4];
#pragma unroll
        for (int s = 0; s < NST; ++s)
#pragma unroll
            for (int st = 0; st < 4; ++st) {
                c[s][st] = (f32x4){0.f, 0.f, 0.f, 0.f};
#pragma unroll
                for (int kk = 0; kk < 2; ++kk)
                    c[s][st] = __builtin_amdgcn_mfma_f32_16x16x32_bf16(ah[st][kk], qf[s][kk], c[s][st], 0, 0, 0);
            }
        // ---- softmax per state ----
        float scale[NST];
        unsigned pw[NST][4][2];
#pragma unroll
        for (int s = 0; s < NST; ++s) {
            float tmax = -INFINITY;
#pragma unroll
            for (int st = 0; st < 4; ++st)
#pragma unroll
                for (int j = 0; j < 4; ++j) {
                    int key = kt * 64 + st * 16 + g * 4 + j;
                    float sv = (key <= 256) ? c[s][st][j] : -INFINITY;
                    c[s][st][j] = sv;
                    tmax = fmaxf(tmax, sv);
                }
            tmax = fmaxf(tmax, __shfl_xor(tmax, 16));
            tmax = fmaxf(tmax, __shfl_xor(tmax, 32));
            float mn = fmaxf(m[s], tmax);
            scale[s] = __expf(m[s] - mn);
            float psum = 0.f;
#pragma unroll
            for (int st = 0; st < 4; ++st) {
                float p0 = __expf(c[s][st][0] - mn), p1 = __expf(c[s][st][1] - mn);
                float p2 = __expf(c[s][st][2] - mn), p3 = __expf(c[s][st][3] - mn);
                psum += (p0 + p1) + (p2 + p3);
                pw[s][st][0] = pack2(p0, p1);
                pw[s][st][1] = pack2(p2, p3);
            }
            psum += __shfl_xor(psum, 16);
            psum += __shfl_xor(psum, 32);
            lsum[s] = lsum[s] * scale[s] + psum;
            m[s] = mn;
        }
        // ---- P -> LDS + O rescale ----
#pragma unroll
        for (int s = 0; s < NST; ++s) {
            char* pwave = (char*)&Plds[w][s][0];
#pragma unroll
            for (int st = 0; st < 4; ++st) {
                int off = (lq * 128 + st * 32 + g * 8) ^ xorm;
                *(u32x2*)(pwave + off) = (u32x2){pw[s][st][0], pw[s][st][1]};
            }
#pragma unroll
            for (int dt = 0; dt < 4; ++dt) {
                o[s][dt][0] *= scale[s]; o[s][dt][1] *= scale[s];
                o[s][dt][2] *= scale[s]; o[s][dt][3] *= scale[s];
            }
        }
        // ---- PV (V fragments shared): mfma(V^T, P) -> C[d][q=lq] ----
#pragma unroll
        for (int kk = 0; kk < 2; ++kk) {
            short8 pf[NST];
#pragma unroll
            for (int s = 0; s < NST; ++s) {
                int roff = (lq * 128 + kk * 64 + g * 16) ^ xorm;
                pf[s] = *(const short8*)((char*)&Plds[w][s][0] + roff);
            }
#pragma unroll
            for (int dt = 0; dt < 4; ++dt) {
                short8 vf = *(const short8*)(vp + (size_t)(dt * 16 + lq) * SKV + kt * 64 + kk * 32 + g * 8);
#pragma unroll
                for (int s = 0; s < NST; ++s)
                    o[s][dt] = __builtin_amdgcn_mfma_f32_16x16x32_bf16(vf, pf[s], o[s][dt], 0, 0, 0);
            }
        }
    }
#pragma unroll
    for (int s = 0; s < NST; ++s) {
        if (qr0[s] < S_LEN) {
            float inv = 1.0f / lsum[s];
            float* trow = tok + ((size_t)n * S_LEN + qr0[s]) * 768 + h * 64 + g * 4;
#pragma unroll
            for (int dt = 0; dt < 4; ++dt) {
                float4 old = *(const float4*)(trow + dt * 16);
                old.x += o[s][dt][0] * inv;
                old.y += o[s][dt][1] * inv;
                old.z += o[s][dt][2] * inv;
                old.w += o[s][dt][3] * inv;
                *(float4*)(trow + dt * 16) = old;
            }
        }
    }
}

// ---------------- fast exact-erf GELU (A&S 7.1.26, abs err 1.5e-7) ----------------
__device__ __forceinline__ float gelu_fast(float x) {
    float s = fabsf(x) * 0.70710678118654752f;
    float t = 1.0f / (1.0f + 0.3275911f * s);
    float y = t * (0.254829592f + t * (-0.284496736f + t * (1.421413741f +
              t * (-1.453152027f + t * 1.061405429f))));
    float erfa = 1.0f - y * __expf(-s * s);
    float erfv = copysignf(erfa, x);
    return 0.5f * x * (1.0f + erfv);
}

// ---------------- bf16 MFMA GEMM, 128x128, BK=64, double-buffered glds (2-phase) -----------
// MODE 0: bias + gelu -> bf16 out.  MODE 1: (+bias) + accumulate fp32 out.
template <int MODE>
__global__ __launch_bounds__(256) void mfma_gemm(const ushort_t* __restrict__ A,
                                                 const ushort_t* __restrict__ B,
                                                 const float* __restrict__ bias,
                                                 void* __restrict__ Cv,
                                                 int K, int lda, int ldb, int ldc) {
    __shared__ ushort_t As[2][128 * 64];
    __shared__ ushort_t Bs[2][128 * 64];
    int t = threadIdx.x;
    int lane = t & 63, wid = t >> 6;
    int wr = wid >> 1, wc = wid & 1;
    int bm = blockIdx.y, bn = blockIdx.x;
    const ushort_t* Ag = A + (size_t)(bm * 128) * lda;
    const ushort_t* Bg = B + (size_t)(bn * 128) * ldb;
    int srow = t >> 3;                       // 0..31
    int swz = ((t & 7) ^ (srow & 7)) * 8;    // source pre-swizzle
    int wbase = (t & 192) * 8;               // wave-uniform LDS chunk base (shorts)
    int frow = lane & 15, g = lane >> 4;
    f32x4 acc[4][4];
#pragma unroll
    for (int m = 0; m < 4; ++m)
#pragma unroll
        for (int n = 0; n < 4; ++n) acc[m][n] = (f32x4){0.f, 0.f, 0.f, 0.f};

    auto STAGE = [&](int buf, int k0) {
#pragma unroll
        for (int u = 0; u < 4; ++u) {
            glds16(Ag + (size_t)(u * 32 + srow) * lda + k0 + swz, &As[buf][u * 2048 + wbase]);
            glds16(Bg + (size_t)(u * 32 + srow) * ldb + k0 + swz, &Bs[buf][u * 2048 + wbase]);
        }
    };
    STAGE(0, 0);
    asm volatile("s_waitcnt vmcnt(0)" ::: "memory");
    __builtin_amdgcn_s_barrier();
    int nt = K >> 6;
    int cur = 0;
    for (int it = 0; it < nt; ++it) {
        if (it + 1 < nt) STAGE(cur ^ 1, (it + 1) * 64);   // issue next tile early
        const ushort_t* Ab = &As[cur][0];
        const ushort_t* Bb = &Bs[cur][0];
#pragma unroll
        for (int kk = 0; kk < 2; ++kk) {
            short8 af[4], bfr[4];
#pragma unroll
            for (int mi = 0; mi < 4; ++mi) {
                int r = wr * 64 + mi * 16 + frow;
                af[mi] = *(const short8*)&Ab[r * 64 + ((kk * 4 + g) ^ (r & 7)) * 8];
            }
#pragma unroll
            for (int ni = 0; ni < 4; ++ni) {
                int r = wc * 64 + ni * 16 + frow;
                bfr[ni] = *(const short8*)&Bb[r * 64 + ((kk * 4 + g) ^ (r & 7)) * 8];
            }
            // swapped: C[row=A-row(frow)][col=B-row(g*4+j)]
#pragma unroll
            for (int mi = 0; mi < 4; ++mi)
#pragma unroll
                for (int ni = 0; ni < 4; ++ni)
                    acc[mi][ni] = __builtin_amdgcn_mfma_f32_16x16x32_bf16(bfr[ni], af[mi], acc[mi][ni], 0, 0, 0);
        }
        if (it + 1 < nt) {
            asm volatile("s_waitcnt vmcnt(0) lgkmcnt(0)" ::: "memory");
            __builtin_amdgcn_s_barrier();
            cur ^= 1;
        }
    }
    int row0 = bm * 128 + wr * 64 + frow;
    int col0 = bn * 128 + wc * 64 + g * 4;
#pragma unroll
    for (int n = 0; n < 4; ++n) {
        int col = col0 + n * 16;
        float4 bb = {0.f, 0.f, 0.f, 0.f};
        if (bias) bb = *(const float4*)(bias + col);
#pragma unroll
        for (int mi = 0; mi < 4; ++mi) {
            int row = row0 + mi * 16;
            f32x4 a = acc[mi][n];
            float v0 = a[0] + bb.x, v1 = a[1] + bb.y, v2 = a[2] + bb.z, v3 = a[3] + bb.w;
            if (MODE == 0) {
                v0 = gelu_fast(v0); v1 = gelu_fast(v1); v2 = gelu_fast(v2); v3 = gelu_fast(v3);
                *(u32x2*)((ushort_t*)Cv + (size_t)row * ldc + col) =
                    (u32x2){pack2(v0, v1), pack2(v2, v3)};
            } else {
                float* cp = (float*)Cv + (size_t)row * ldc + col;
                float4 old = *(const float4*)cp;
                old.x += v0; old.y += v1; old.z += v2; old.w += v3;
                *(float4*)cp = old;
            }
        }
    }
}

// ---------------- classifier head + softmax ----------------
__global__ __launch_bounds__(64) void head_kernel(const float* __restrict__ tok,
                                                  const float* __restrict__ Whead,
                                                  const float* __restrict__ bhead,
                                                  float* __restrict__ out) {
    int n = blockIdx.x;
    int t = threadIdx.x;
    __shared__ float logits[OUT_DIM];
    if (t < OUT_DIM) {
        float acc = bhead[t];
        const float* xr = tok + (size_t)n * S_LEN * 768;
        const float* w = Whead + t * 768;
        for (int d = 0; d < 768; ++d) acc += xr[d] * w[d];
        logits[t] = acc;
    }
    __syncthreads();
    if (t == 0) {
        float m = -INFINITY;
        for (int o = 0; o < OUT_DIM; ++o) m = fmaxf(m, logits[o]);
        float ssum = 0.f;
        float e[OUT_DIM];
        for (int o = 0; o < OUT_DIM; ++o) { e[o] = expf(logits[o] - m); ssum += e[o]; }
        float inv = 1.0f / ssum;
        for (int o = 0; o < OUT_DIM; ++o) out[n * OUT_DIM + o] = e[o] * inv;
    }
}

extern "C" void kernel_launch(void* const* d_in, const int* in_sizes, int n_in,
                              void* d_out, int out_size, void* d_ws, size_t ws_size,
                              hipStream_t stream) {
    const float* images = (const float*)d_in[0];
    const float* Wemb   = (const float*)d_in[1];
    const float* bemb   = (const float*)d_in[2];
    const float* cls    = (const float*)d_in[3];
    const float* Wq     = (const float*)d_in[4];
    const float* bq     = (const float*)d_in[5];
    const float* Wk     = (const float*)d_in[6];
    const float* bk     = (const float*)d_in[7];
    const float* Wv     = (const float*)d_in[8];
    const float* bv     = (const float*)d_in[9];
    const float* ln1_g  = (const float*)d_in[10];
    const float* ln1_b  = (const float*)d_in[11];
    const float* ln2_g  = (const float*)d_in[12];
    const float* ln2_b  = (const float*)d_in[13];
    const float* W1     = (const float*)d_in[14];
    const float* b1     = (const float*)d_in[15];
    const float* W2     = (const float*)d_in[16];
    const float* b2     = (const float*)d_in[17];
    const float* Whead  = (const float*)d_in[18];
    const float* bhead  = (const float*)d_in[19];
    float* out = (float*)d_out;

    const size_t TOKP = (size_t)R_PAD * D_MODEL;               // 12,681,216
    const size_t QKSZ = (size_t)N_IMG * H_HEADS * S_LEN * 64;  // 12,632,064
    const size_t VTSZ = (size_t)N_IMG * H_HEADS * 64 * SKV;    // 15,728,640
    const size_t WSZ  = (size_t)F_HID * D_MODEL;               // 2,359,296
    float* ws   = (float*)d_ws;
    float* pos  = ws;                                          // 197,376 f32
    float* tok  = pos + 197376;                                // TOKP f32
    ushort_t* xbf  = (ushort_t*)(tok + TOKP);                  // TOKP bf16
    ushort_t* qhb  = xbf + TOKP;                               // QKSZ
    ushort_t* khb  = qhb + QKSZ;                               // QKSZ
    ushort_t* vtb  = khb + QKSZ;                               // VTSZ
    ushort_t* wqkvbf = vtb + VTSZ;                             // 147,456
    ushort_t* w1bf = wqkvbf + H_HEADS * 192 * 64;              // full layer W1
    ushort_t* w2bf = w1bf + WSZ;                               // full layer W2
    ushort_t* hid_full = w2bf + WSZ;                           // R_PAD*F_HID bf16 (if ws allows)

    const size_t hid_bytes = (size_t)R_PAD * F_HID * 2;
    const size_t needed = ((char*)hid_full - (char*)d_ws) + hid_bytes;
    int nchunk = (ws_size >= needed) ? 1 : 2;
    int FC = F_HID / nchunk;
    ushort_t* hid = (nchunk == 1) ? hid_full : qhb;   // fallback: overlay q/k region

    pos_kernel<<<S_LEN, 256, 0, stream>>>(pos);
    embed_kernel<<<R_ROWS, 256, 0, stream>>>(images, Wemb, bemb, cls, pos, tok);

    for (int l = 0; l < L_LAYERS; ++l) {
        const size_t wqkv_off = (size_t)l * H_HEADS * 64 * 64;
        const size_t bqkv_off = (size_t)l * H_HEADS * 64;
        ln_kernel<<<R_ROWS / 4, 256, 0, stream>>>(tok, ln1_g + l * 768, ln1_b + l * 768, xbf);
        conv_layer<<<4752, 256, 0, stream>>>(
            Wq + wqkv_off, Wk + wqkv_off, Wv + wqkv_off,
            W1 + (size_t)l * WSZ, W2 + (size_t)l * WSZ,
            wqkvbf, w1bf, w2bf);
        qkv_mfma<<<dim3(R_PAD / 128, H_HEADS), 256, 0, stream>>>(
            xbf, wqkvbf, bq + bqkv_off, bk + bqkv_off, bv + bqkv_off, qhb, khb, vtb);
        attn_mfma<2><<<N_IMG * H_HEADS * 2, 256, 0, stream>>>(qhb, khb, vtb, tok);
        attn_mfma<1><<<N_IMG * H_HEADS, 256, 0, stream>>>(qhb, khb, vtb, tok);
        ln_kernel<<<R_ROWS / 4, 256, 0, stream>>>(tok, ln2_g + l * 768, ln2_b + l * 768, xbf);
        for (int c = 0; c < nchunk; ++c) {
            int c0 = c * FC;
            mfma_gemm<0><<<dim3(FC / 128, R_PAD / 128), 256, 0, stream>>>(
                xbf, w1bf + (size_t)c0 * D_MODEL, b1 + (size_t)l * F_HID + c0, hid,
                768, 768, 768, FC);
            mfma_gemm<1><<<dim3(D_MODEL / 128, R_PAD / 128), 256, 0, stream>>>(
                hid, w2bf + c0, (c == 0) ? (b2 + (size_t)l * D_MODEL) : (const float*)nullptr,
                tok, FC, FC, F_HID, D_MODEL);
        }
    }
    head_kernel<<<N_IMG, 64, 0, stream>>>(tok, Whead, bhead, out);
}

// Round 7
// 4822.564 us; speedup vs baseline: 22.0431x; 1.0365x over previous
//
#include <hip/hip_runtime.h>
#include <math.h>
#include <stdint.h>

#define N_IMG 64
#define S_LEN 257
#define D_MODEL 768
#define H_HEADS 12
#define L_LAYERS 12
#define F_HID 3072
#define OUT_DIM 10
#define R_ROWS (N_IMG * S_LEN)   // 16448
#define R_PAD 16512              // 129 * 128
#define SKV 320                  // padded key count for vT

typedef unsigned short ushort_t;
typedef __attribute__((ext_vector_type(4))) float f32x4;
typedef __attribute__((ext_vector_type(8))) short short8;
typedef __attribute__((ext_vector_type(2))) unsigned int u32x2;

__device__ __forceinline__ ushort_t f2bf(float x) {
    unsigned u = __float_as_uint(x);
    u += 0x7fffu + ((u >> 16) & 1u);
    return (ushort_t)(u >> 16);
}
__device__ __forceinline__ unsigned pack2(float a, float b) {
    return (unsigned)f2bf(a) | ((unsigned)f2bf(b) << 16);
}

// async global->LDS, 16B per lane; dest = wave-uniform base + lane*16
__device__ __forceinline__ void glds16(const ushort_t* g, const ushort_t* l) {
    __builtin_amdgcn_global_load_lds(
        (const __attribute__((address_space(1))) unsigned int*)(uintptr_t)g,
        (__attribute__((address_space(3))) unsigned int*)(uintptr_t)l,
        16, 0, 0);
}

// ---------------- positional embedding (double precision, matches numpy f64) ----------------
__global__ __launch_bounds__(256) void pos_kernel(float* __restrict__ pos) {
    int i = blockIdx.x;
    int t = threadIdx.x;
    for (int u = 0; u < 3; ++u) {
        int j = t + 256 * u;
        double e = (double)(j & ~1) / 768.0;
        double angle = (double)i * exp(-e * 9.210340371976184);
        double v = (j & 1) ? cos(angle) : sin(angle);
        pos[i * 768 + j] = (float)v;
    }
}

// ---------------- patch embed + cls + pos ----------------
__global__ __launch_bounds__(256) void embed_kernel(const float* __restrict__ images,
                                                    const float* __restrict__ Wemb,
                                                    const float* __restrict__ bemb,
                                                    const float* __restrict__ cls,
                                                    const float* __restrict__ pos,
                                                    float* __restrict__ tok) {
    int b = blockIdx.x;
    int n = b / S_LEN, s = b % S_LEN;
    int t = threadIdx.x;
    __shared__ float p[16];
    if (s > 0 && t < 16) p[t] = images[n * 4096 + (s - 1) * 16 + t];
    __syncthreads();
    for (int u = 0; u < 3; ++u) {
        int d = t + 256 * u;
        float acc;
        if (s == 0) {
            acc = cls[d];
        } else {
            acc = bemb[d];
            const float4* w = (const float4*)(Wemb + d * 16);
            float4 w0 = w[0], w1 = w[1], w2 = w[2], w3 = w[3];
            acc += p[0] * w0.x + p[1] * w0.y + p[2] * w0.z + p[3] * w0.w;
            acc += p[4] * w1.x + p[5] * w1.y + p[6] * w1.z + p[7] * w1.w;
            acc += p[8] * w2.x + p[9] * w2.y + p[10] * w2.z + p[11] * w2.w;
            acc += p[12] * w3.x + p[13] * w3.y + p[14] * w3.z + p[15] * w3.w;
        }
        tok[(size_t)b * 768 + d] = acc + pos[s * 768 + d];
    }
}

// ---------------- layernorm -> bf16 : one wave per row ----------------
__global__ __launch_bounds__(256) void ln_kernel(const float* __restrict__ x,
                                                 const float* __restrict__ g,
                                                 const float* __restrict__ b,
                                                 ushort_t* __restrict__ y) {
    int row = blockIdx.x * 4 + (threadIdx.x >> 6);
    int lane = threadIdx.x & 63;
    const float* xr = x + (size_t)row * 768 + lane * 4;
    float4 a0 = *(const float4*)xr;
    float4 a1 = *(const float4*)(xr + 256);
    float4 a2 = *(const float4*)(xr + 512);
    float s = (a0.x + a0.y + a0.z + a0.w) + (a1.x + a1.y + a1.z + a1.w) + (a2.x + a2.y + a2.z + a2.w);
    float sq = a0.x*a0.x + a0.y*a0.y + a0.z*a0.z + a0.w*a0.w
             + a1.x*a1.x + a1.y*a1.y + a1.z*a1.z + a1.w*a1.w
             + a2.x*a2.x + a2.y*a2.y + a2.z*a2.z + a2.w*a2.w;
    for (int o = 32; o; o >>= 1) {
        s += __shfl_xor(s, o);
        sq += __shfl_xor(sq, o);
    }
    float mu = s * (1.0f / 768.0f);
    float var = sq * (1.0f / 768.0f) - mu * mu;
    float rs = rsqrtf(var + 1e-5f);
    ushort_t* yr = y + (size_t)row * 768 + lane * 4;
#pragma unroll
    for (int i = 0; i < 3; ++i) {
        float4 av = (i == 0) ? a0 : (i == 1) ? a1 : a2;
        const float4 gg = *(const float4*)(g + lane * 4 + i * 256);
        const float4 bb = *(const float4*)(b + lane * 4 + i * 256);
        float o0 = (av.x - mu) * rs * gg.x + bb.x;
        float o1 = (av.y - mu) * rs * gg.y + bb.y;
        float o2 = (av.z - mu) * rs * gg.z + bb.z;
        float o3 = (av.w - mu) * rs * gg.w + bb.w;
        *(u32x2*)(yr + i * 256) = (u32x2){pack2(o0, o1), pack2(o2, o3)};
    }
}

// ---------------- per-layer weight conversion: wqkv pack + full W1 + full W2 ----------------
__global__ __launch_bounds__(256) void conv_layer(const float* __restrict__ Wq,
                                                  const float* __restrict__ Wk,
                                                  const float* __restrict__ Wv,
                                                  const float* __restrict__ W1l,
                                                  const float* __restrict__ W2l,
                                                  ushort_t* __restrict__ wqkvbf,
                                                  ushort_t* __restrict__ w1bf,
                                                  ushort_t* __restrict__ w2bf) {
    const int NQKV = H_HEADS * 192 * 64;       // 147456
    const int NW = F_HID * D_MODEL;            // 2359296
    int idx = (blockIdx.x * 256 + threadIdx.x) * 4;
    if (idx < NQKV) {
        int h = idx / (192 * 64);
        int rem = idx - h * 192 * 64;
        int o3 = rem >> 6, d = rem & 63;
        const float* src;
        int o;
        if (o3 < 64)       { src = Wq; o = o3; }
        else if (o3 < 128) { src = Wk; o = o3 - 64; }
        else               { src = Wv; o = o3 - 128; }
        float4 v = *(const float4*)(src + ((size_t)(h * 64 + o)) * 64 + d);
        *(u32x2*)(wqkvbf + idx) = (u32x2){pack2(v.x, v.y), pack2(v.z, v.w)};
    } else if (idx < NQKV + NW) {
        int i = idx - NQKV;
        float4 v = *(const float4*)(W1l + i);
        *(u32x2*)(w1bf + i) = (u32x2){pack2(v.x, v.y), pack2(v.z, v.w)};
    } else {
        int i = idx - NQKV - NW;
        float4 v = *(const float4*)(W2l + i);
        *(u32x2*)(w2bf + i) = (u32x2){pack2(v.x, v.y), pack2(v.z, v.w)};
    }
}

// ---------------- MFMA QKV: block = (128 token rows, head); swapped-operand epilogue -------
__global__ __launch_bounds__(256) void qkv_mfma(const ushort_t* __restrict__ xbf,
                                                const ushort_t* __restrict__ wqkv,
                                                const float* __restrict__ bq,
                                                const float* __restrict__ bk,
                                                const float* __restrict__ bv,
                                                ushort_t* __restrict__ qhb,
                                                ushort_t* __restrict__ khb,
                                                ushort_t* __restrict__ vtb) {
    __shared__ ushort_t As[128 * 64];
    int rt = blockIdx.x;            // 0..128
    int h = blockIdx.y;
    int t = threadIdx.x, lane = t & 63, wid = t >> 6;
    int wr = wid >> 1, wc = wid & 1;     // wave tile: 64 rows x 96 cols
    {
        int lr = t >> 3, lg = t & 7;
#pragma unroll
        for (int u = 0; u < 4; ++u) {
            int r = u * 32 + lr;
            int grow = rt * 128 + r;
            if (grow >= R_ROWS) grow = R_ROWS - 1;
            short8 a = *(const short8*)(xbf + (size_t)grow * 768 + h * 64 + lg * 8);
            *(short8*)&As[r * 64 + (lg ^ (r & 7)) * 8] = a;
        }
    }
    __syncthreads();
    int frow = lane & 15, g = lane >> 4;
    const ushort_t* wb = wqkv + (size_t)h * (192 * 64);
    f32x4 acc[4][6];
#pragma unroll
    for (int m = 0; m < 4; ++m)
#pragma unroll
        for (int n = 0; n < 6; ++n) acc[m][n] = (f32x4){0.f, 0.f, 0.f, 0.f};
#pragma unroll
    for (int kk = 0; kk < 2; ++kk) {
        short8 af[4], bfr[6];
#pragma unroll
        for (int m = 0; m < 4; ++m) {
            int r = wr * 64 + m * 16 + frow;
            af[m] = *(const short8*)&As[r * 64 + ((kk * 4 + g) ^ (r & 7)) * 8];
        }
#pragma unroll
        for (int n = 0; n < 6; ++n)
            bfr[n] = *(const short8*)(wb + (size_t)(wc * 96 + n * 16 + frow) * 64 + kk * 32 + g * 8);
        // swapped: C[row=token(frow)][col=output(g*4+j)]
#pragma unroll
        for (int m = 0; m < 4; ++m)
#pragma unroll
            for (int n = 0; n < 6; ++n)
                acc[m][n] = __builtin_amdgcn_mfma_f32_16x16x32_bf16(bfr[n], af[m], acc[m][n], 0, 0, 0);
    }
#pragma unroll
    for (int m = 0; m < 4; ++m) {
        int token = rt * 128 + wr * 64 + m * 16 + frow;
        if (token < R_ROWS) {
            unsigned nimg = (unsigned)token / 257u;
            unsigned s = (unsigned)token - nimg * 257u;
            size_t qk_base = ((size_t)(nimg * H_HEADS + h) * 257 + s) * 64;
            size_t v_base = (size_t)(nimg * H_HEADS + h) * (64 * SKV);
#pragma unroll
            for (int n = 0; n < 6; ++n) {
                int c = wc * 96 + n * 16 + g * 4;
                f32x4 a = acc[m][n];
                if (c < 64) {
                    const float4 bb = *(const float4*)(bq + h * 64 + c);
                    *(u32x2*)(qhb + qk_base + c) = (u32x2){
                        pack2((a[0] + bb.x) * 0.125f, (a[1] + bb.y) * 0.125f),
                        pack2((a[2] + bb.z) * 0.125f, (a[3] + bb.w) * 0.125f)};
                } else if (c < 128) {
                    const float4 bb = *(const float4*)(bk + h * 64 + (c - 64));
                    *(u32x2*)(khb + qk_base + (c - 64)) = (u32x2){
                        pack2(a[0] + bb.x, a[1] + bb.y), pack2(a[2] + bb.z, a[3] + bb.w)};
                } else {
                    const float4 bb = *(const float4*)(bv + h * 64 + (c - 128));
                    vtb[v_base + (size_t)(c - 128 + 0) * SKV + s] = f2bf(a[0] + bb.x);
                    vtb[v_base + (size_t)(c - 128 + 1) * SKV + s] = f2bf(a[1] + bb.y);
                    vtb[v_base + (size_t)(c - 128 + 2) * SKV + s] = f2bf(a[2] + bb.z);
                    vtb[v_base + (size_t)(c - 128 + 3) * SKV + s] = f2bf(a[3] + bb.w);
                }
            }
        }
    }
}

// ---------------- MFMA flash attention: NST q-states per wave share K/V fragment loads ------
// rows covered: base + s*64 + w*16 + lq for s in [0,NST); clamped at 256.
template <int NST>
__global__ __launch_bounds__(256) void attn_mfma(const ushort_t* __restrict__ qh,
                                                 const ushort_t* __restrict__ kh,
                                                 const ushort_t* __restrict__ vT,
                                                 float* __restrict__ tok, int base) {
    __shared__ ushort_t Plds[4][NST][1024];
    int nh = blockIdx.x;
    int h = nh % H_HEADS, n = nh / H_HEADS;
    int t = threadIdx.x, w = t >> 6, lane = t & 63;
    int lq = lane & 15, g = lane >> 4;
    const size_t hoff = ((size_t)n * H_HEADS + h) * (S_LEN * 64);
    const ushort_t* qhp = qh + hoff;
    const ushort_t* khp = kh + hoff;
    const ushort_t* vp  = vT + ((size_t)n * H_HEADS + h) * (64 * SKV);
    const int xorm = (lq & 7) << 4;

    short8 qf[NST][2];
    int qr0[NST];
    float m[NST], lsum[NST];
    f32x4 o[NST][4];
#pragma unroll
    for (int s = 0; s < NST; ++s) {
        int qrow = base + s * 64 + w * 16 + lq;
        qr0[s] = qrow;
        int qcl = qrow > 256 ? 256 : qrow;
#pragma unroll
        for (int kk = 0; kk < 2; ++kk)
            qf[s][kk] = *(const short8*)(qhp + (size_t)qcl * 64 + kk * 32 + g * 8);
        m[s] = -INFINITY; lsum[s] = 0.f;
#pragma unroll
        for (int dt = 0; dt < 4; ++dt) o[s][dt] = (f32x4){0.f, 0.f, 0.f, 0.f};
    }

    for (int kt = 0; kt < 5; ++kt) {
        // ---- K fragments (shared across states) ----
        short8 ah[4][2];
#pragma unroll
        for (int st = 0; st < 4; ++st) {
            int key = kt * 64 + st * 16 + lq;
            int kcl = key > 256 ? 256 : key;
            const ushort_t* krh = khp + (size_t)kcl * 64 + g * 8;
            ah[st][0] = *(const short8*)krh;
            ah[st][1] = *(const short8*)(krh + 32);
        }
        // ---- QK^T for all states ----
        f32x4 c[NST][4];
#pragma unroll
        for (int s = 0; s < NST; ++s)
#pragma unroll
            for (int st = 0; st < 4; ++st) {
                c[s][st] = (f32x4){0.f, 0.f, 0.f, 0.f};
#pragma unroll
                for (int kk = 0; kk < 2; ++kk)
                    c[s][st] = __builtin_amdgcn_mfma_f32_16x16x32_bf16(ah[st][kk], qf[s][kk], c[s][st], 0, 0, 0);
            }
        // ---- softmax per state ----
        float scale[NST];
        unsigned pw[NST][4][2];
#pragma unroll
        for (int s = 0; s < NST; ++s) {
            float tmax = -INFINITY;
#pragma unroll
            for (int st = 0; st < 4; ++st)
#pragma unroll
                for (int j = 0; j < 4; ++j) {
                    int key = kt * 64 + st * 16 + g * 4 + j;
                    float sv = (key <= 256) ? c[s][st][j] : -INFINITY;
                    c[s][st][j] = sv;
                    tmax = fmaxf(tmax, sv);
                }
            tmax = fmaxf(tmax, __shfl_xor(tmax, 16));
            tmax = fmaxf(tmax, __shfl_xor(tmax, 32));
            float mn = fmaxf(m[s], tmax);
            scale[s] = __expf(m[s] - mn);
            float psum = 0.f;
#pragma unroll
            for (int st = 0; st < 4; ++st) {
                float p0 = __expf(c[s][st][0] - mn), p1 = __expf(c[s][st][1] - mn);
                float p2 = __expf(c[s][st][2] - mn), p3 = __expf(c[s][st][3] - mn);
                psum += (p0 + p1) + (p2 + p3);
                pw[s][st][0] = pack2(p0, p1);
                pw[s][st][1] = pack2(p2, p3);
            }
            psum += __shfl_xor(psum, 16);
            psum += __shfl_xor(psum, 32);
            lsum[s] = lsum[s] * scale[s] + psum;
            m[s] = mn;
        }
        // ---- P -> LDS + O rescale ----
#pragma unroll
        for (int s = 0; s < NST; ++s) {
            char* pwave = (char*)&Plds[w][s][0];
#pragma unroll
            for (int st = 0; st < 4; ++st) {
                int off = (lq * 128 + st * 32 + g * 8) ^ xorm;
                *(u32x2*)(pwave + off) = (u32x2){pw[s][st][0], pw[s][st][1]};
            }
#pragma unroll
            for (int dt = 0; dt < 4; ++dt) {
                o[s][dt][0] *= scale[s]; o[s][dt][1] *= scale[s];
                o[s][dt][2] *= scale[s]; o[s][dt][3] *= scale[s];
            }
        }
        // ---- PV (V fragments shared): mfma(V^T, P) -> C[d][q=lq] ----
#pragma unroll
        for (int kk = 0; kk < 2; ++kk) {
            short8 pf[NST];
#pragma unroll
            for (int s = 0; s < NST; ++s) {
                int roff = (lq * 128 + kk * 64 + g * 16) ^ xorm;
                pf[s] = *(const short8*)((char*)&Plds[w][s][0] + roff);
            }
#pragma unroll
            for (int dt = 0; dt < 4; ++dt) {
                short8 vf = *(const short8*)(vp + (size_t)(dt * 16 + lq) * SKV + kt * 64 + kk * 32 + g * 8);
#pragma unroll
                for (int s = 0; s < NST; ++s)
                    o[s][dt] = __builtin_amdgcn_mfma_f32_16x16x32_bf16(vf, pf[s], o[s][dt], 0, 0, 0);
            }
        }
    }
#pragma unroll
    for (int s = 0; s < NST; ++s) {
        if (qr0[s] < S_LEN) {
            float inv = 1.0f / lsum[s];
            float* trow = tok + ((size_t)n * S_LEN + qr0[s]) * 768 + h * 64 + g * 4;
#pragma unroll
            for (int dt = 0; dt < 4; ++dt) {
                float4 old = *(const float4*)(trow + dt * 16);
                old.x += o[s][dt][0] * inv;
                old.y += o[s][dt][1] * inv;
                old.z += o[s][dt][2] * inv;
                old.w += o[s][dt][3] * inv;
                *(float4*)(trow + dt * 16) = old;
            }
        }
    }
}

// ---------------- fast exact-erf GELU (A&S 7.1.26, abs err 1.5e-7) ----------------
__device__ __forceinline__ float gelu_fast(float x) {
    float s = fabsf(x) * 0.70710678118654752f;
    float t = 1.0f / (1.0f + 0.3275911f * s);
    float y = t * (0.254829592f + t * (-0.284496736f + t * (1.421413741f +
              t * (-1.453152027f + t * 1.061405429f))));
    float erfa = 1.0f - y * __expf(-s * s);
    float erfv = copysignf(erfa, x);
    return 0.5f * x * (1.0f + erfv);
}

// ---------------- bf16 MFMA GEMM, 128x128, BK=64, dbuf glds, XCD-chunked block swizzle -----
// MODE 0: bias + gelu -> bf16 out.  MODE 1: (+bias) + accumulate fp32 out.
// 1-D launch; nbn = blocks along N. m204 bijective chunk swizzle: each XCD owns a
// contiguous run of bm panels so all bn-blocks of a panel share that XCD's L2.
template <int MODE>
__global__ __launch_bounds__(256) void mfma_gemm(const ushort_t* __restrict__ A,
                                                 const ushort_t* __restrict__ B,
                                                 const float* __restrict__ bias,
                                                 void* __restrict__ Cv,
                                                 int K, int lda, int ldb, int ldc, int nbn) {
    __shared__ ushort_t As[2][128 * 64];
    __shared__ ushort_t Bs[2][128 * 64];
    int nwg = gridDim.x;
    int orig = blockIdx.x;
    int xcd = orig & 7, idx = orig >> 3;
    int q8 = nwg >> 3, r8 = nwg & 7;
    int cbase = (xcd < r8) ? xcd * (q8 + 1) : r8 * (q8 + 1) + (xcd - r8) * q8;
    int swz = cbase + idx;
    int bm = swz / nbn, bn = swz - bm * nbn;

    int t = threadIdx.x;
    int lane = t & 63, wid = t >> 6;
    int wr = wid >> 1, wc = wid & 1;
    const ushort_t* Ag = A + (size_t)(bm * 128) * lda;
    const ushort_t* Bg = B + (size_t)(bn * 128) * ldb;
    int srow = t >> 3;                       // 0..31
    int swzo = ((t & 7) ^ (srow & 7)) * 8;   // source pre-swizzle
    int wbase = (t & 192) * 8;               // wave-uniform LDS chunk base (shorts)
    int frow = lane & 15, g = lane >> 4;
    f32x4 acc[4][4];
#pragma unroll
    for (int m = 0; m < 4; ++m)
#pragma unroll
        for (int n = 0; n < 4; ++n) acc[m][n] = (f32x4){0.f, 0.f, 0.f, 0.f};

    auto STAGE = [&](int buf, int k0) {
#pragma unroll
        for (int u = 0; u < 4; ++u) {
            glds16(Ag + (size_t)(u * 32 + srow) * lda + k0 + swzo, &As[buf][u * 2048 + wbase]);
            glds16(Bg + (size_t)(u * 32 + srow) * ldb + k0 + swzo, &Bs[buf][u * 2048 + wbase]);
        }
    };
    STAGE(0, 0);
    asm volatile("s_waitcnt vmcnt(0)" ::: "memory");
    __builtin_amdgcn_s_barrier();
    int nt = K >> 6;
    int cur = 0;
    for (int it = 0; it < nt; ++it) {
        if (it + 1 < nt) STAGE(cur ^ 1, (it + 1) * 64);   // issue next tile early
        const ushort_t* Ab = &As[cur][0];
        const ushort_t* Bb = &Bs[cur][0];
#pragma unroll
        for (int kk = 0; kk < 2; ++kk) {
            short8 af[4], bfr[4];
#pragma unroll
            for (int mi = 0; mi < 4; ++mi) {
                int r = wr * 64 + mi * 16 + frow;
                af[mi] = *(const short8*)&Ab[r * 64 + ((kk * 4 + g) ^ (r & 7)) * 8];
            }
#pragma unroll
            for (int ni = 0; ni < 4; ++ni) {
                int r = wc * 64 + ni * 16 + frow;
                bfr[ni] = *(const short8*)&Bb[r * 64 + ((kk * 4 + g) ^ (r & 7)) * 8];
            }
            // swapped: C[row=A-row(frow)][col=B-row(g*4+j)]
#pragma unroll
            for (int mi = 0; mi < 4; ++mi)
#pragma unroll
                for (int ni = 0; ni < 4; ++ni)
                    acc[mi][ni] = __builtin_amdgcn_mfma_f32_16x16x32_bf16(bfr[ni], af[mi], acc[mi][ni], 0, 0, 0);
        }
        if (it + 1 < nt) {
            asm volatile("s_waitcnt vmcnt(0) lgkmcnt(0)" ::: "memory");
            __builtin_amdgcn_s_barrier();
            cur ^= 1;
        }
    }
    int row0 = bm * 128 + wr * 64 + frow;
    int col0 = bn * 128 + wc * 64 + g * 4;
#pragma unroll
    for (int n = 0; n < 4; ++n) {
        int col = col0 + n * 16;
        float4 bb = {0.f, 0.f, 0.f, 0.f};
        if (bias) bb = *(const float4*)(bias + col);
#pragma unroll
        for (int mi = 0; mi < 4; ++mi) {
            int row = row0 + mi * 16;
            f32x4 a = acc[mi][n];
            float v0 = a[0] + bb.x, v1 = a[1] + bb.y, v2 = a[2] + bb.z, v3 = a[3] + bb.w;
            if (MODE == 0) {
                v0 = gelu_fast(v0); v1 = gelu_fast(v1); v2 = gelu_fast(v2); v3 = gelu_fast(v3);
                *(u32x2*)((ushort_t*)Cv + (size_t)row * ldc + col) =
                    (u32x2){pack2(v0, v1), pack2(v2, v3)};
            } else {
                float* cp = (float*)Cv + (size_t)row * ldc + col;
                float4 old = *(const float4*)cp;
                old.x += v0; old.y += v1; old.z += v2; old.w += v3;
                *(float4*)cp = old;
            }
        }
    }
}

// ---------------- classifier head + softmax ----------------
__global__ __launch_bounds__(64) void head_kernel(const float* __restrict__ tok,
                                                  const float* __restrict__ Whead,
                                                  const float* __restrict__ bhead,
                                                  float* __restrict__ out) {
    int n = blockIdx.x;
    int t = threadIdx.x;
    __shared__ float logits[OUT_DIM];
    if (t < OUT_DIM) {
        float acc = bhead[t];
        const float* xr = tok + (size_t)n * S_LEN * 768;
        const float* w = Whead + t * 768;
        for (int d = 0; d < 768; ++d) acc += xr[d] * w[d];
        logits[t] = acc;
    }
    __syncthreads();
    if (t == 0) {
        float m = -INFINITY;
        for (int o = 0; o < OUT_DIM; ++o) m = fmaxf(m, logits[o]);
        float ssum = 0.f;
        float e[OUT_DIM];
        for (int o = 0; o < OUT_DIM; ++o) { e[o] = expf(logits[o] - m); ssum += e[o]; }
        float inv = 1.0f / ssum;
        for (int o = 0; o < OUT_DIM; ++o) out[n * OUT_DIM + o] = e[o] * inv;
    }
}

extern "C" void kernel_launch(void* const* d_in, const int* in_sizes, int n_in,
                              void* d_out, int out_size, void* d_ws, size_t ws_size,
                              hipStream_t stream) {
    const float* images = (const float*)d_in[0];
    const float* Wemb   = (const float*)d_in[1];
    const float* bemb   = (const float*)d_in[2];
    const float* cls    = (const float*)d_in[3];
    const float* Wq     = (const float*)d_in[4];
    const float* bq     = (const float*)d_in[5];
    const float* Wk     = (const float*)d_in[6];
    const float* bk     = (const float*)d_in[7];
    const float* Wv     = (const float*)d_in[8];
    const float* bv     = (const float*)d_in[9];
    const float* ln1_g  = (const float*)d_in[10];
    const float* ln1_b  = (const float*)d_in[11];
    const float* ln2_g  = (const float*)d_in[12];
    const float* ln2_b  = (const float*)d_in[13];
    const float* W1     = (const float*)d_in[14];
    const float* b1     = (const float*)d_in[15];
    const float* W2     = (const float*)d_in[16];
    const float* b2     = (const float*)d_in[17];
    const float* Whead  = (const float*)d_in[18];
    const float* bhead  = (const float*)d_in[19];
    float* out = (float*)d_out;

    const size_t TOKP = (size_t)R_PAD * D_MODEL;               // 12,681,216
    const size_t QKSZ = (size_t)N_IMG * H_HEADS * S_LEN * 64;  // 12,632,064
    const size_t VTSZ = (size_t)N_IMG * H_HEADS * 64 * SKV;    // 15,728,640
    const size_t WSZ  = (size_t)F_HID * D_MODEL;               // 2,359,296
    float* ws   = (float*)d_ws;
    float* pos  = ws;                                          // 197,376 f32
    float* tok  = pos + 197376;                                // TOKP f32
    ushort_t* xbf  = (ushort_t*)(tok + TOKP);                  // TOKP bf16
    ushort_t* qhb  = xbf + TOKP;                               // QKSZ
    ushort_t* khb  = qhb + QKSZ;                               // QKSZ
    ushort_t* vtb  = khb + QKSZ;                               // VTSZ
    ushort_t* wqkvbf = vtb + VTSZ;                             // 147,456
    ushort_t* w1bf = wqkvbf + H_HEADS * 192 * 64;              // full layer W1
    ushort_t* w2bf = w1bf + WSZ;                               // full layer W2
    ushort_t* hid_full = w2bf + WSZ;                           // R_PAD*F_HID bf16 (if ws allows)

    const size_t hid_bytes = (size_t)R_PAD * F_HID * 2;
    const size_t needed = ((char*)hid_full - (char*)d_ws) + hid_bytes;
    int nchunk = (ws_size >= needed) ? 1 : 2;
    int FC = F_HID / nchunk;
    ushort_t* hid = (nchunk == 1) ? hid_full : qhb;   // fallback: overlay q/k region

    pos_kernel<<<S_LEN, 256, 0, stream>>>(pos);
    embed_kernel<<<R_ROWS, 256, 0, stream>>>(images, Wemb, bemb, cls, pos, tok);

    for (int l = 0; l < L_LAYERS; ++l) {
        const size_t wqkv_off = (size_t)l * H_HEADS * 64 * 64;
        const size_t bqkv_off = (size_t)l * H_HEADS * 64;
        ln_kernel<<<R_ROWS / 4, 256, 0, stream>>>(tok, ln1_g + l * 768, ln1_b + l * 768, xbf);
        conv_layer<<<4752, 256, 0, stream>>>(
            Wq + wqkv_off, Wk + wqkv_off, Wv + wqkv_off,
            W1 + (size_t)l * WSZ, W2 + (size_t)l * WSZ,
            wqkvbf, w1bf, w2bf);
        qkv_mfma<<<dim3(R_PAD / 128, H_HEADS), 256, 0, stream>>>(
            xbf, wqkvbf, bq + bqkv_off, bk + bqkv_off, bv + bqkv_off, qhb, khb, vtb);
        attn_mfma<2><<<N_IMG * H_HEADS, 256, 0, stream>>>(qhb, khb, vtb, tok, 0);
        attn_mfma<3><<<N_IMG * H_HEADS, 256, 0, stream>>>(qhb, khb, vtb, tok, 128);
        ln_kernel<<<R_ROWS / 4, 256, 0, stream>>>(tok, ln2_g + l * 768, ln2_b + l * 768, xbf);
        for (int c = 0; c < nchunk; ++c) {
            int c0 = c * FC;
            mfma_gemm<0><<<(FC / 128) * (R_PAD / 128), 256, 0, stream>>>(
                xbf, w1bf + (size_t)c0 * D_MODEL, b1 + (size_t)l * F_HID + c0, hid,
                768, 768, 768, FC, FC / 128);
            mfma_gemm<1><<<(D_MODEL / 128) * (R_PAD / 128), 256, 0, stream>>>(
                hid, w2bf + c0, (c == 0) ? (b2 + (size_t)l * D_MODEL) : (const float*)nullptr,
                tok, FC, FC, F_HID, D_MODEL, D_MODEL / 128);
        }
    }
    head_kernel<<<N_IMG, 64, 0, stream>>>(tok, Whead, bhead, out);
}